// Round 1
// baseline (478.551 us; speedup 1.0000x reference)
//
#include <hip/hip_runtime.h>
#include <hip/hip_bf16.h>
#include <math.h>

#define S_LEN 2048
#define H_DIM 2048
#define NH 16
#define Q_LORA 1536
#define KV_LORA 512
#define D_NOPE 128
#define D_ROPE 64
#define D_V 128
#define D_QK 192

typedef unsigned short ushort_t;
typedef __attribute__((ext_vector_type(8))) short short8;
typedef __attribute__((ext_vector_type(4))) float f32x4;

__device__ __forceinline__ ushort_t f2bf(float f) {
    unsigned int u = __float_as_uint(f);
    u = (u + 0x7FFFu + ((u >> 16) & 1u)) >> 16;
    return (ushort_t)u;
}
__device__ __forceinline__ float bf2f(ushort_t u) {
    return __uint_as_float(((unsigned int)u) << 16);
}

__device__ __forceinline__ void storeC(float* p, float v) { *p = v; }
__device__ __forceinline__ void storeC(ushort_t* p, float v) { *p = f2bf(v); }

__device__ __forceinline__ void gload_lds16(const ushort_t* g, ushort_t* l) {
    __builtin_amdgcn_global_load_lds(
        (const __attribute__((address_space(1))) unsigned int*)(const void*)g,
        (__attribute__((address_space(3))) unsigned int*)(void*)l, 16, 0, 0);
}

// 16-lane DPP-row reductions (pure VALU)
__device__ __forceinline__ float dpp_max16(float x) {
    x = fmaxf(x, __int_as_float(__builtin_amdgcn_update_dpp(0, __float_as_int(x), 0xB1, 0xF, 0xF, true)));
    x = fmaxf(x, __int_as_float(__builtin_amdgcn_update_dpp(0, __float_as_int(x), 0x4E, 0xF, 0xF, true)));
    x = fmaxf(x, __int_as_float(__builtin_amdgcn_update_dpp(0, __float_as_int(x), 0x124, 0xF, 0xF, true)));
    x = fmaxf(x, __int_as_float(__builtin_amdgcn_update_dpp(0, __float_as_int(x), 0x128, 0xF, 0xF, true)));
    return x;
}
__device__ __forceinline__ float dpp_sum16(float x) {
    x += __int_as_float(__builtin_amdgcn_update_dpp(0, __float_as_int(x), 0xB1, 0xF, 0xF, true));
    x += __int_as_float(__builtin_amdgcn_update_dpp(0, __float_as_int(x), 0x4E, 0xF, 0xF, true));
    x += __int_as_float(__builtin_amdgcn_update_dpp(0, __float_as_int(x), 0x124, 0xF, 0xF, true));
    x += __int_as_float(__builtin_amdgcn_update_dpp(0, __float_as_int(x), 0x128, 0xF, 0xF, true));
    return x;
}

// -------- unified conversion: hs f32->bf16 + 5 weight transposes, one launch --------
__device__ __forceinline__ void convT_body(
    const float* __restrict__ W, ushort_t* __restrict__ Wt,
    int K, int N, int n0, int k0, float (*tile)[33])
{
    const int tr = threadIdx.x >> 5, tc = threadIdx.x & 31;
    #pragma unroll
    for (int i = 0; i < 4; ++i) {
        int r = tr + i * 8;
        float v = 0.f;
        if (n0 + tc < N) v = W[(size_t)(k0 + r) * N + n0 + tc];
        tile[r][tc] = v;
    }
    __syncthreads();
    #pragma unroll
    for (int i = 0; i < 4; ++i) {
        int r = tr + i * 8;
        Wt[(size_t)(n0 + r) * K + k0 + tc] = f2bf(tile[tc][r]);
    }
}

__global__ __launch_bounds__(256) void unified_conv(
    const float* __restrict__ hs, ushort_t* __restrict__ hs16,
    const float* __restrict__ Wqa, const float* __restrict__ Wkva,
    const float* __restrict__ Wqb, const float* __restrict__ Wkvb,
    const float* __restrict__ Wo,
    ushort_t* __restrict__ WcatT, ushort_t* __restrict__ WqbT,
    ushort_t* __restrict__ WkvbT, ushort_t* __restrict__ WoT)
{
    __shared__ float tile[32][33];
    int b = blockIdx.x;
    if (b < 4096) {   // hs elementwise
        int base = (b * 256 + threadIdx.x) * 4;
        float4 v = *(const float4*)(hs + base);
        hs16[base + 0] = f2bf(v.x);
        hs16[base + 1] = f2bf(v.y);
        hs16[base + 2] = f2bf(v.z);
        hs16[base + 3] = f2bf(v.w);
        return;
    }
    b -= 4096;
    const float* W; ushort_t* Wt; int K, N, nbx;
    if (b < 3072)        {            W = Wqa;  Wt = WcatT;                              K = 2048; N = 1536; nbx = 48;  }
    else if (b < 4352)   { b -= 3072; W = Wkva; Wt = WcatT + (size_t)Q_LORA * H_DIM;     K = 2048; N = 576;  nbx = 20;  }
    else if (b < 8960)   { b -= 4352; W = Wqb;  Wt = WqbT;                               K = 1536; N = 3072; nbx = 96;  }
    else if (b < 11008)  { b -= 8960; W = Wkvb; Wt = WkvbT;                              K = 512;  N = 4096; nbx = 128; }
    else                 { b -= 11008; W = Wo;  Wt = WoT;                                K = 2048; N = 2048; nbx = 64;  }
    convT_body(W, Wt, K, N, (b % nbx) * 32, (b / nbx) * 32, tile);
}

// ------- fused: rmsnorm-q (blocks 0..2047) + rmsnorm-kv (2048..4095) + rope-k (4096..) -------
__global__ __launch_bounds__(256) void fused_norm_ropek(
    const ushort_t* __restrict__ cat16r, ushort_t* __restrict__ qa16,
    ushort_t* __restrict__ ckv16n, ushort_t* __restrict__ kpe16,
    const float* __restrict__ qlnw, const float* __restrict__ klnw)
{
    __shared__ float red[4];
    const int b = blockIdx.x;
    if (b < 4096) {
        const bool isQ = (b < 2048);
        const int row = isQ ? b : b - 2048;
        const int K = isQ ? Q_LORA : KV_LORA;
        const ushort_t* x = cat16r + (size_t)row * 2176 + (isQ ? 0 : Q_LORA);
        ushort_t* y = (isQ ? qa16 + (size_t)row * Q_LORA : ckv16n + (size_t)row * KV_LORA);
        const float* wv = isQ ? qlnw : klnw;
        float ss = 0.f;
        for (int i = threadIdx.x; i < K; i += 256) { float v = bf2f(x[i]); ss += v * v; }
        #pragma unroll
        for (int off = 32; off > 0; off >>= 1) ss += __shfl_down(ss, off);
        int lane = threadIdx.x & 63, wid = threadIdx.x >> 6;
        if (lane == 0) red[wid] = ss;
        __syncthreads();
        float tot = red[0] + red[1] + red[2] + red[3];
        float rs = rsqrtf(tot / (float)K + 1e-6f);
        for (int i = threadIdx.x; i < K; i += 256)
            y[i] = f2bf(bf2f(x[i]) * rs * wv[i]);
    } else {
        int idx = (b - 4096) * 256 + threadIdx.x;
        if (idx >= S_LEN * 32) return;
        int i = idx & 31;
        int s = idx >> 5;
        float inv = powf(10000.0f, -(2.0f * i) / 64.0f);
        float ang = (float)s * inv;
        float c = cosf(ang), sn = sinf(ang);
        const ushort_t* p = cat16r + (size_t)s * 2176 + Q_LORA + KV_LORA;
        ushort_t* q = kpe16 + (size_t)s * D_ROPE;
        float x1 = bf2f(p[i]), x2 = bf2f(p[i + 32]);
        q[i]      = f2bf(x1 * c - x2 * sn);
        q[i + 32] = f2bf(x2 * c + x1 * sn);
    }
}

// ---------------- V transpose: kv16[s][h*256+128+dv] -> v16t[h][dv][s] ----------------
__global__ __launch_bounds__(256) void conv_vT_kernel(
    const ushort_t* __restrict__ kv, ushort_t* __restrict__ v16t)
{
    __shared__ ushort_t tile[32][33];
    const int h = blockIdx.z;
    const int s0 = blockIdx.x * 32, d0 = blockIdx.y * 32;
    const int tr = threadIdx.x >> 5, tc = threadIdx.x & 31;
    #pragma unroll
    for (int i = 0; i < 4; ++i) {
        int r = tr + i * 8;  // s
        tile[r][tc] = kv[(size_t)(s0 + r) * 4096 + h * 256 + D_NOPE + d0 + tc];
    }
    __syncthreads();
    #pragma unroll
    for (int i = 0; i < 4; ++i) {
        int r = tr + i * 8;  // dv
        v16t[(size_t)h * D_V * S_LEN + (size_t)(d0 + r) * S_LEN + s0 + tc] = tile[tc][r];
    }
}

// ---- MFMA GEMM body, 64x128 (MxN) tile, BK=64 (two 32-chunks per barrier) ----
template <typename CT>
__device__ __forceinline__ void gemm_body_bk64(
    const ushort_t* __restrict__ A, const ushort_t* __restrict__ Bt,
    CT* __restrict__ C, int N, int K, int m0, int n0,
    ushort_t* Al, ushort_t* Bl)  // Al: 2*64*32, Bl: 2*128*32
{
    const int tid = threadIdx.x;
    const int lane = tid & 63;
    const int w = tid >> 6;
    const int lm = lane & 15, quad = lane >> 4;
    const int wr = w >> 1, wc = w & 1;

    f32x4 acc[2][4];
    #pragma unroll
    for (int a = 0; a < 2; ++a)
        #pragma unroll
        for (int b = 0; b < 4; ++b) acc[a][b] = (f32x4){0.f, 0.f, 0.f, 0.f};

    const int rrow = tid >> 2;
    const int rcol = (tid & 3) * 8;

    for (int k0 = 0; k0 < K; k0 += 64) {
        __syncthreads();
        #pragma unroll
        for (int c = 0; c < 2; ++c) {
            gload_lds16(A + (size_t)(m0 + rrow) * K + k0 + c * 32 + rcol,
                        Al + c * 2048 + tid * 8);
            #pragma unroll
            for (int i = 0; i < 2; ++i)
                gload_lds16(Bt + (size_t)(n0 + i * 64 + rrow) * K + k0 + c * 32 + rcol,
                            Bl + c * 4096 + (i * 256 + tid) * 8);
        }
        __syncthreads();

        #pragma unroll
        for (int c = 0; c < 2; ++c) {
            short8 af[2], bf[4];
            #pragma unroll
            for (int t = 0; t < 2; ++t)
                af[t] = *(const short8*)(Al + c * 2048 + (wr * 32 + t * 16 + lm) * 32 + quad * 8);
            #pragma unroll
            for (int t = 0; t < 4; ++t)
                bf[t] = *(const short8*)(Bl + c * 4096 + (wc * 64 + t * 16 + lm) * 32 + quad * 8);
            #pragma unroll
            for (int mt = 0; mt < 2; ++mt)
                #pragma unroll
                for (int nt = 0; nt < 4; ++nt)
                    acc[mt][nt] = __builtin_amdgcn_mfma_f32_16x16x32_bf16(
                        af[mt], bf[nt], acc[mt][nt], 0, 0, 0);
        }
    }

    #pragma unroll
    for (int mt = 0; mt < 2; ++mt)
        #pragma unroll
        for (int nt = 0; nt < 4; ++nt)
            #pragma unroll
            for (int r = 0; r < 4; ++r) {
                int row = m0 + wr * 32 + mt * 16 + quad * 4 + r;
                int col = n0 + wc * 64 + nt * 16 + lm;
                storeC(&C[(size_t)row * N + col], acc[mt][nt][r]);
            }
}

template <typename CT>
__global__ __launch_bounds__(256) void mfma_gemm_bt(
    const ushort_t* __restrict__ A, const ushort_t* __restrict__ Bt,
    CT* __restrict__ C, int N, int K)
{
    __shared__ ushort_t Al[2 * 64 * 32];
    __shared__ ushort_t Bl[2 * 128 * 32];
    gemm_body_bk64<CT>(A, Bt, C, N, K, blockIdx.y * 64, blockIdx.x * 128, Al, Bl);
}

__global__ __launch_bounds__(256) void mfma_gemm_dual(
    const ushort_t* __restrict__ A1, const ushort_t* __restrict__ Bt1,
    ushort_t* __restrict__ C1, int N1, int K1, int nb1,
    const ushort_t* __restrict__ A2, const ushort_t* __restrict__ Bt2,
    ushort_t* __restrict__ C2, int N2, int K2)
{
    __shared__ ushort_t Al[2 * 64 * 32];
    __shared__ ushort_t Bl[2 * 128 * 32];
    int g = blockIdx.x;
    if (g < nb1) {
        int nbx = N1 / 128;
        gemm_body_bk64<ushort_t>(A1, Bt1, C1, N1, K1, (g / nbx) * 64, (g % nbx) * 128, Al, Bl);
    } else {
        g -= nb1;
        int nbx = N2 / 128;
        gemm_body_bk64<ushort_t>(A2, Bt2, C2, N2, K2, (g / nbx) * 64, (g % nbx) * 128, Al, Bl);
    }
}

// online-softmax update for one 16x64 score tile in C layout (DPP); P -> ps[16][72]
__device__ __forceinline__ void softmax_step(
    f32x4 s[4], int k0, int qw, int lm, int quad,
    float m_[4], float l_[4], f32x4 O[8], ushort_t* ps)
{
    const float scale = 0.07216878364870322f;  // 192^-0.5
    #pragma unroll
    for (int r = 0; r < 4; ++r) {
        int qrow = qw + quad * 4 + r;
        float a[4];
        #pragma unroll
        for (int st = 0; st < 4; ++st)
            a[st] = (k0 + st * 16 + lm <= qrow) ? s[st][r] * scale : -1e30f;
        float mx = dpp_max16(fmaxf(fmaxf(a[0], a[1]), fmaxf(a[2], a[3])));
        float mn = fmaxf(m_[r], mx);
        float p[4];
        #pragma unroll
        for (int st = 0; st < 4; ++st) p[st] = __expf(a[st] - mn);
        float alpha = __expf(m_[r] - mn);
        float psum = dpp_sum16((p[0] + p[1]) + (p[2] + p[3]));
        l_[r] = l_[r] * alpha + psum;
        m_[r] = mn;
        #pragma unroll
        for (int c = 0; c < 8; ++c) O[c][r] *= alpha;
        #pragma unroll
        for (int st = 0; st < 4; ++st)
            ps[(quad * 4 + r) * 72 + st * 16 + lm] = f2bf(p[st]);
    }
}

// ---- MFMA flash attention, UNSTAGED: K/Kr/V^T fragments read directly from
// global (all L2/L3-resident; staging them in LDS was pure overhead — the
// kernel was latency-bound at 6 waves/CU with a vmcnt(0)+barrier drain per
// 64-key tile and 8-way LDS bank conflicts on every fragment read).
// No __syncthreads, LDS = Ps only (4.5 KB), waves fully independent,
// per-wave causal loop bound. Fused RoPE-q kept. ----
__global__ __launch_bounds__(128) void mla_attn_kernel(
    const ushort_t* __restrict__ qb, const ushort_t* __restrict__ kvb,
    const ushort_t* __restrict__ kpe, const ushort_t* __restrict__ v16t,
    ushort_t* __restrict__ aout16)
{
    __shared__ ushort_t Ps[2][16][72];     // 4.5 KB, per-wave private

    const int h = blockIdx.x;
    const int q0 = 32 * (63 - blockIdx.y);  // heavy-first
    const int w = threadIdx.x >> 6;         // 0..1
    const int lane = threadIdx.x & 63;
    const int lm = lane & 15, quad = lane >> 4;
    const int qw = q0 + 16 * w;
    ushort_t* myPs = &Ps[w][0][0];

    // Q fragments (un-roped source) + fused RoPE on chunks 4/5
    short8 qf[6];
    #pragma unroll
    for (int f = 0; f < 6; ++f)
        qf[f] = *(const short8*)(qb + (size_t)(qw + lm) * 3072 + h * 192 + f * 32 + quad * 8);
    {
        float srow = (float)(qw + lm);
        #pragma unroll
        for (int j = 0; j < 8; ++j) {
            int i = quad * 8 + j;
            float inv = powf(10000.0f, -(2.0f * i) / 64.0f);
            float ang = srow * inv;
            float c = cosf(ang), sn = sinf(ang);
            float x1 = bf2f((ushort_t)qf[4][j]);
            float x2 = bf2f((ushort_t)qf[5][j]);
            qf[4][j] = (short)f2bf(x1 * c - x2 * sn);
            qf[5][j] = (short)f2bf(x2 * c + x1 * sn);
        }
    }

    f32x4 O[8];
    #pragma unroll
    for (int c = 0; c < 8; ++c) O[c] = (f32x4){0.f, 0.f, 0.f, 0.f};
    float m_[4] = {-1e30f, -1e30f, -1e30f, -1e30f};
    float l_[4] = {0.f, 0.f, 0.f, 0.f};

    const ushort_t* kn_base = kvb + (size_t)h * 256;          // + key*4096 + f*32 + quad*8
    const ushort_t* vt_base = v16t + (size_t)h * 128 * S_LEN; // + dv*S_LEN + key

    const int kend = qw + 16;   // per-wave causal bound
    for (int k0 = 0; k0 < kend; k0 += 64) {
        // ---- QK^T: fragments straight from global (L2-resident) ----
        f32x4 s[4];
        #pragma unroll
        for (int st = 0; st < 4; ++st) s[st] = (f32x4){0.f, 0.f, 0.f, 0.f};
        #pragma unroll
        for (int st = 0; st < 4; ++st) {
            const ushort_t* krow = kn_base + (size_t)(k0 + st * 16 + lm) * 4096 + quad * 8;
            #pragma unroll
            for (int f = 0; f < 4; ++f) {
                short8 kf = *(const short8*)(krow + f * 32);
                s[st] = __builtin_amdgcn_mfma_f32_16x16x32_bf16(qf[f], kf, s[st], 0, 0, 0);
            }
            const ushort_t* krp = kpe + (size_t)(k0 + st * 16 + lm) * 64 + quad * 8;
            short8 kr0 = *(const short8*)(krp);
            short8 kr1 = *(const short8*)(krp + 32);
            s[st] = __builtin_amdgcn_mfma_f32_16x16x32_bf16(qf[4], kr0, s[st], 0, 0, 0);
            s[st] = __builtin_amdgcn_mfma_f32_16x16x32_bf16(qf[5], kr1, s[st], 0, 0, 0);
        }

        softmax_step(s, k0, qw, lm, quad, m_, l_, O, myPs);

        asm volatile("s_waitcnt lgkmcnt(0)" ::: "memory");
        short8 pf0 = *(const short8*)(myPs + lm * 72 + quad * 8);
        short8 pf1 = *(const short8*)(myPs + lm * 72 + 32 + quad * 8);
        #pragma unroll
        for (int c = 0; c < 8; ++c) {
            const ushort_t* vr = vt_base + (size_t)(c * 16 + lm) * S_LEN + k0 + quad * 8;
            short8 vf0 = *(const short8*)(vr);
            short8 vf1 = *(const short8*)(vr + 32);
            O[c] = __builtin_amdgcn_mfma_f32_16x16x32_bf16(pf0, vf0, O[c], 0, 0, 0);
            O[c] = __builtin_amdgcn_mfma_f32_16x16x32_bf16(pf1, vf1, O[c], 0, 0, 0);
        }
    }
    // epilogue
    #pragma unroll
    for (int c = 0; c < 8; ++c)
        #pragma unroll
        for (int r = 0; r < 4; ++r) {
            int qrow = qw + quad * 4 + r;
            aout16[(size_t)qrow * 2048 + h * D_V + c * 16 + lm] = f2bf(O[c][r] / l_[r]);
        }
}

extern "C" void kernel_launch(void* const* d_in, const int* in_sizes, int n_in,
                              void* d_out, int out_size, void* d_ws, size_t ws_size,
                              hipStream_t stream)
{
    (void)in_sizes; (void)n_in; (void)out_size; (void)ws_size;
    const float* hs   = (const float*)d_in[0];
    const float* Wqa  = (const float*)d_in[1];
    const float* qlnw = (const float*)d_in[2];
    const float* Wqb  = (const float*)d_in[3];
    const float* Wkva = (const float*)d_in[4];
    const float* klnw = (const float*)d_in[5];
    const float* Wkvb = (const float*)d_in[6];
    const float* Wo   = (const float*)d_in[7];
    float* out = (float*)d_out;

    ushort_t* p = (ushort_t*)d_ws;
    ushort_t* hs16   = p; p += (size_t)S_LEN * H_DIM;
    ushort_t* WcatT  = p; p += (size_t)2176 * H_DIM;     // [Wqa^T 1536 ; Wkva^T 640] x 2048
    ushort_t* WqbT   = p; p += (size_t)3072 * Q_LORA;
    ushort_t* WkvbT  = p; p += (size_t)4096 * KV_LORA;
    ushort_t* WoT    = p; p += (size_t)H_DIM * H_DIM;
    ushort_t* cat16r = p; p += (size_t)S_LEN * 2176;     // [qa_raw | ckv_raw | kpe_raw | pad]
    ushort_t* qa16   = p; p += (size_t)S_LEN * Q_LORA;
    ushort_t* qbuf16 = p; p += (size_t)S_LEN * 3072;
    ushort_t* ckv16n = p; p += (size_t)S_LEN * KV_LORA;
    ushort_t* kpe16  = p; p += (size_t)S_LEN * D_ROPE;
    ushort_t* kv16   = p; p += (size_t)S_LEN * 4096;
    ushort_t* v16t   = p; p += (size_t)NH * D_V * S_LEN;
    ushort_t* aout16 = p; p += (size_t)S_LEN * 2048;

    // 1. all conversions in one launch (hs + 5 weight transposes)
    unified_conv<<<19200, 256, 0, stream>>>(
        hs, hs16, Wqa, Wkva, Wqb, Wkvb, Wo, WcatT, WqbT, WkvbT, WoT);
    // 2. cat16r = hs16 @ WcatT^T  [2048 x 2176, K=2048]  (fused Wqa + Wkva)
    mfma_gemm_bt<ushort_t><<<dim3(2176 / 128, S_LEN / 64), 256, 0, stream>>>(
        hs16, WcatT, cat16r, 2176, H_DIM);
    // 3. fused rmsnorm-q / rmsnorm-kv / rope-k
    fused_norm_ropek<<<4096 + 256, 256, 0, stream>>>(cat16r, qa16, ckv16n, kpe16, qlnw, klnw);
    // 4. grouped GEMM: qbuf16 = qa16 @ WqbT^T [2048x3072,K=1536] + kv16 = ckv16n @ WkvbT^T [2048x4096,K=512]
    mfma_gemm_dual<<<768 + 1024, 256, 0, stream>>>(
        qa16, WqbT, qbuf16, 3072, Q_LORA, 768,
        ckv16n, WkvbT, kv16, 4096, KV_LORA);
    // 5. V transpose
    conv_vT_kernel<<<dim3(S_LEN / 32, D_V / 32, NH), 256, 0, stream>>>(kv16, v16t);
    // 6. attention (unstaged fragments + fused RoPE-q)
    mla_attn_kernel<<<dim3(NH, 64), 128, 0, stream>>>(qbuf16, kv16, kpe16, v16t, aout16);
    // 7. out = aout16 @ WoT^T [2048 x 2048, K=2048], fp32 store
    mfma_gemm_bt<float><<<dim3(H_DIM / 128, S_LEN / 64), 256, 0, stream>>>(
        aout16, WoT, out, H_DIM, H_DIM);
}

// Round 2
// 361.820 us; speedup vs baseline: 1.3226x; 1.3226x over previous
//
#include <hip/hip_runtime.h>
#include <hip/hip_bf16.h>
#include <math.h>

#define S_LEN 2048
#define H_DIM 2048
#define NH 16
#define Q_LORA 1536
#define KV_LORA 512
#define D_NOPE 128
#define D_ROPE 64
#define D_V 128
#define D_QK 192

typedef unsigned short ushort_t;
typedef __attribute__((ext_vector_type(8))) short short8;
typedef __attribute__((ext_vector_type(4))) float f32x4;

__device__ __forceinline__ ushort_t f2bf(float f) {
    unsigned int u = __float_as_uint(f);
    u = (u + 0x7FFFu + ((u >> 16) & 1u)) >> 16;
    return (ushort_t)u;
}
__device__ __forceinline__ float bf2f(ushort_t u) {
    return __uint_as_float(((unsigned int)u) << 16);
}

__device__ __forceinline__ void storeC(float* p, float v) { *p = v; }
__device__ __forceinline__ void storeC(ushort_t* p, float v) { *p = f2bf(v); }

__device__ __forceinline__ void gload_lds16(const ushort_t* g, ushort_t* l) {
    __builtin_amdgcn_global_load_lds(
        (const __attribute__((address_space(1))) unsigned int*)(const void*)g,
        (__attribute__((address_space(3))) unsigned int*)(void*)l, 16, 0, 0);
}

// 16-lane DPP-row reductions (pure VALU)
__device__ __forceinline__ float dpp_max16(float x) {
    x = fmaxf(x, __int_as_float(__builtin_amdgcn_update_dpp(0, __float_as_int(x), 0xB1, 0xF, 0xF, true)));
    x = fmaxf(x, __int_as_float(__builtin_amdgcn_update_dpp(0, __float_as_int(x), 0x4E, 0xF, 0xF, true)));
    x = fmaxf(x, __int_as_float(__builtin_amdgcn_update_dpp(0, __float_as_int(x), 0x124, 0xF, 0xF, true)));
    x = fmaxf(x, __int_as_float(__builtin_amdgcn_update_dpp(0, __float_as_int(x), 0x128, 0xF, 0xF, true)));
    return x;
}
__device__ __forceinline__ float dpp_sum16(float x) {
    x += __int_as_float(__builtin_amdgcn_update_dpp(0, __float_as_int(x), 0xB1, 0xF, 0xF, true));
    x += __int_as_float(__builtin_amdgcn_update_dpp(0, __float_as_int(x), 0x4E, 0xF, 0xF, true));
    x += __int_as_float(__builtin_amdgcn_update_dpp(0, __float_as_int(x), 0x124, 0xF, 0xF, true));
    x += __int_as_float(__builtin_amdgcn_update_dpp(0, __float_as_int(x), 0x128, 0xF, 0xF, true));
    return x;
}

// -------- unified conversion: hs f32->bf16 + 5 weight transposes, one launch --------
__device__ __forceinline__ void convT_body(
    const float* __restrict__ W, ushort_t* __restrict__ Wt,
    int K, int N, int n0, int k0, float (*tile)[33])
{
    const int tr = threadIdx.x >> 5, tc = threadIdx.x & 31;
    #pragma unroll
    for (int i = 0; i < 4; ++i) {
        int r = tr + i * 8;
        float v = 0.f;
        if (n0 + tc < N) v = W[(size_t)(k0 + r) * N + n0 + tc];
        tile[r][tc] = v;
    }
    __syncthreads();
    #pragma unroll
    for (int i = 0; i < 4; ++i) {
        int r = tr + i * 8;
        Wt[(size_t)(n0 + r) * K + k0 + tc] = f2bf(tile[tc][r]);
    }
}

__global__ __launch_bounds__(256) void unified_conv(
    const float* __restrict__ hs, ushort_t* __restrict__ hs16,
    const float* __restrict__ Wqa, const float* __restrict__ Wkva,
    const float* __restrict__ Wqb, const float* __restrict__ Wkvb,
    const float* __restrict__ Wo,
    ushort_t* __restrict__ WcatT, ushort_t* __restrict__ WqbT,
    ushort_t* __restrict__ WkvbT, ushort_t* __restrict__ WoT)
{
    __shared__ float tile[32][33];
    int b = blockIdx.x;
    if (b < 4096) {   // hs elementwise
        int base = (b * 256 + threadIdx.x) * 4;
        float4 v = *(const float4*)(hs + base);
        hs16[base + 0] = f2bf(v.x);
        hs16[base + 1] = f2bf(v.y);
        hs16[base + 2] = f2bf(v.z);
        hs16[base + 3] = f2bf(v.w);
        return;
    }
    b -= 4096;
    const float* W; ushort_t* Wt; int K, N, nbx;
    if (b < 3072)        {            W = Wqa;  Wt = WcatT;                              K = 2048; N = 1536; nbx = 48;  }
    else if (b < 4352)   { b -= 3072; W = Wkva; Wt = WcatT + (size_t)Q_LORA * H_DIM;     K = 2048; N = 576;  nbx = 20;  }
    else if (b < 8960)   { b -= 4352; W = Wqb;  Wt = WqbT;                               K = 1536; N = 3072; nbx = 96;  }
    else if (b < 11008)  { b -= 8960; W = Wkvb; Wt = WkvbT;                              K = 512;  N = 4096; nbx = 128; }
    else                 { b -= 11008; W = Wo;  Wt = WoT;                                K = 2048; N = 2048; nbx = 64;  }
    convT_body(W, Wt, K, N, (b % nbx) * 32, (b / nbx) * 32, tile);
}

// ------- fused: rmsnorm-q (blocks 0..2047) + rmsnorm-kv (2048..4095) + rope-k (4096..) -------
__global__ __launch_bounds__(256) void fused_norm_ropek(
    const ushort_t* __restrict__ cat16r, ushort_t* __restrict__ qa16,
    ushort_t* __restrict__ ckv16n, ushort_t* __restrict__ kpe16,
    const float* __restrict__ qlnw, const float* __restrict__ klnw)
{
    __shared__ float red[4];
    const int b = blockIdx.x;
    if (b < 4096) {
        const bool isQ = (b < 2048);
        const int row = isQ ? b : b - 2048;
        const int K = isQ ? Q_LORA : KV_LORA;
        const ushort_t* x = cat16r + (size_t)row * 2176 + (isQ ? 0 : Q_LORA);
        ushort_t* y = (isQ ? qa16 + (size_t)row * Q_LORA : ckv16n + (size_t)row * KV_LORA);
        const float* wv = isQ ? qlnw : klnw;
        float ss = 0.f;
        for (int i = threadIdx.x; i < K; i += 256) { float v = bf2f(x[i]); ss += v * v; }
        #pragma unroll
        for (int off = 32; off > 0; off >>= 1) ss += __shfl_down(ss, off);
        int lane = threadIdx.x & 63, wid = threadIdx.x >> 6;
        if (lane == 0) red[wid] = ss;
        __syncthreads();
        float tot = red[0] + red[1] + red[2] + red[3];
        float rs = rsqrtf(tot / (float)K + 1e-6f);
        for (int i = threadIdx.x; i < K; i += 256)
            y[i] = f2bf(bf2f(x[i]) * rs * wv[i]);
    } else {
        int idx = (b - 4096) * 256 + threadIdx.x;
        if (idx >= S_LEN * 32) return;
        int i = idx & 31;
        int s = idx >> 5;
        float inv = powf(10000.0f, -(2.0f * i) / 64.0f);
        float ang = (float)s * inv;
        float c = cosf(ang), sn = sinf(ang);
        const ushort_t* p = cat16r + (size_t)s * 2176 + Q_LORA + KV_LORA;
        ushort_t* q = kpe16 + (size_t)s * D_ROPE;
        float x1 = bf2f(p[i]), x2 = bf2f(p[i + 32]);
        q[i]      = f2bf(x1 * c - x2 * sn);
        q[i + 32] = f2bf(x2 * c + x1 * sn);
    }
}

// ---------------- V transpose: kv16[s][h*256+128+dv] -> v16t[h][dv][s] ----------------
__global__ __launch_bounds__(256) void conv_vT_kernel(
    const ushort_t* __restrict__ kv, ushort_t* __restrict__ v16t)
{
    __shared__ ushort_t tile[32][33];
    const int h = blockIdx.z;
    const int s0 = blockIdx.x * 32, d0 = blockIdx.y * 32;
    const int tr = threadIdx.x >> 5, tc = threadIdx.x & 31;
    #pragma unroll
    for (int i = 0; i < 4; ++i) {
        int r = tr + i * 8;  // s
        tile[r][tc] = kv[(size_t)(s0 + r) * 4096 + h * 256 + D_NOPE + d0 + tc];
    }
    __syncthreads();
    #pragma unroll
    for (int i = 0; i < 4; ++i) {
        int r = tr + i * 8;  // dv
        v16t[(size_t)h * D_V * S_LEN + (size_t)(d0 + r) * S_LEN + s0 + tc] = tile[tc][r];
    }
}

// ---- MFMA GEMM body, 64x128 (MxN) tile, BK=64 (two 32-chunks per barrier) ----
template <typename CT>
__device__ __forceinline__ void gemm_body_bk64(
    const ushort_t* __restrict__ A, const ushort_t* __restrict__ Bt,
    CT* __restrict__ C, int N, int K, int m0, int n0,
    ushort_t* Al, ushort_t* Bl)  // Al: 2*64*32, Bl: 2*128*32
{
    const int tid = threadIdx.x;
    const int lane = tid & 63;
    const int w = tid >> 6;
    const int lm = lane & 15, quad = lane >> 4;
    const int wr = w >> 1, wc = w & 1;

    f32x4 acc[2][4];
    #pragma unroll
    for (int a = 0; a < 2; ++a)
        #pragma unroll
        for (int b = 0; b < 4; ++b) acc[a][b] = (f32x4){0.f, 0.f, 0.f, 0.f};

    const int rrow = tid >> 2;
    const int rcol = (tid & 3) * 8;

    for (int k0 = 0; k0 < K; k0 += 64) {
        __syncthreads();
        #pragma unroll
        for (int c = 0; c < 2; ++c) {
            gload_lds16(A + (size_t)(m0 + rrow) * K + k0 + c * 32 + rcol,
                        Al + c * 2048 + tid * 8);
            #pragma unroll
            for (int i = 0; i < 2; ++i)
                gload_lds16(Bt + (size_t)(n0 + i * 64 + rrow) * K + k0 + c * 32 + rcol,
                            Bl + c * 4096 + (i * 256 + tid) * 8);
        }
        __syncthreads();

        #pragma unroll
        for (int c = 0; c < 2; ++c) {
            short8 af[2], bf[4];
            #pragma unroll
            for (int t = 0; t < 2; ++t)
                af[t] = *(const short8*)(Al + c * 2048 + (wr * 32 + t * 16 + lm) * 32 + quad * 8);
            #pragma unroll
            for (int t = 0; t < 4; ++t)
                bf[t] = *(const short8*)(Bl + c * 4096 + (wc * 64 + t * 16 + lm) * 32 + quad * 8);
            #pragma unroll
            for (int mt = 0; mt < 2; ++mt)
                #pragma unroll
                for (int nt = 0; nt < 4; ++nt)
                    acc[mt][nt] = __builtin_amdgcn_mfma_f32_16x16x32_bf16(
                        af[mt], bf[nt], acc[mt][nt], 0, 0, 0);
        }
    }

    #pragma unroll
    for (int mt = 0; mt < 2; ++mt)
        #pragma unroll
        for (int nt = 0; nt < 4; ++nt)
            #pragma unroll
            for (int r = 0; r < 4; ++r) {
                int row = m0 + wr * 32 + mt * 16 + quad * 4 + r;
                int col = n0 + wc * 64 + nt * 16 + lm;
                storeC(&C[(size_t)row * N + col], acc[mt][nt][r]);
            }
}

template <typename CT>
__global__ __launch_bounds__(256) void mfma_gemm_bt(
    const ushort_t* __restrict__ A, const ushort_t* __restrict__ Bt,
    CT* __restrict__ C, int N, int K)
{
    __shared__ ushort_t Al[2 * 64 * 32];
    __shared__ ushort_t Bl[2 * 128 * 32];
    gemm_body_bk64<CT>(A, Bt, C, N, K, blockIdx.y * 64, blockIdx.x * 128, Al, Bl);
}

__global__ __launch_bounds__(256) void mfma_gemm_dual(
    const ushort_t* __restrict__ A1, const ushort_t* __restrict__ Bt1,
    ushort_t* __restrict__ C1, int N1, int K1, int nb1,
    const ushort_t* __restrict__ A2, const ushort_t* __restrict__ Bt2,
    ushort_t* __restrict__ C2, int N2, int K2)
{
    __shared__ ushort_t Al[2 * 64 * 32];
    __shared__ ushort_t Bl[2 * 128 * 32];
    int g = blockIdx.x;
    if (g < nb1) {
        int nbx = N1 / 128;
        gemm_body_bk64<ushort_t>(A1, Bt1, C1, N1, K1, (g / nbx) * 64, (g % nbx) * 128, Al, Bl);
    } else {
        g -= nb1;
        int nbx = N2 / 128;
        gemm_body_bk64<ushort_t>(A2, Bt2, C2, N2, K2, (g / nbx) * 64, (g % nbx) * 128, Al, Bl);
    }
}

// online-softmax update for one 16x32 score tile in C layout (DPP); P -> ps[16][36]
__device__ __forceinline__ void softmax_step32(
    f32x4 s[2], int k0, int qw, int lm, int quad,
    float m_[4], float l_[4], f32x4 O[8], ushort_t* ps)
{
    const float scale = 0.07216878364870322f;  // 192^-0.5
    #pragma unroll
    for (int r = 0; r < 4; ++r) {
        int qrow = qw + quad * 4 + r;
        float a0 = (k0 + lm      <= qrow) ? s[0][r] * scale : -1e30f;
        float a1 = (k0 + 16 + lm <= qrow) ? s[1][r] * scale : -1e30f;
        float mx = dpp_max16(fmaxf(a0, a1));
        float mn = fmaxf(m_[r], mx);
        float p0 = __expf(a0 - mn);
        float p1 = __expf(a1 - mn);
        float alpha = __expf(m_[r] - mn);
        float psum = dpp_sum16(p0 + p1);
        l_[r] = l_[r] * alpha + psum;
        m_[r] = mn;
        #pragma unroll
        for (int c = 0; c < 8; ++c) O[c][r] *= alpha;
        ps[(quad * 4 + r) * 36 + lm]      = f2bf(p0);
        ps[(quad * 4 + r) * 36 + 16 + lm] = f2bf(p1);
    }
}

// ---- MFMA flash attention, PIPELINED + SWIZZLED:
// Round-1 lesson: grid gives only 2 waves/SIMD -> direct-global fragments are
// latency-death. Round-0 lesson: staged version pays full staging latency
// per tile (vmcnt(0)+barrier drain) + 8-way LDS bank conflicts.
// This version: 4-wave blocks (QBLK=64, staging shared -> half the staging
// instr/wave, 8 waves/CU), KVBLK=32 double-buffered prefetch pipeline with
// counted s_waitcnt vmcnt(5) across raw s_barrier (catalog T3/T4 minimum),
// and XOR bank-swizzle (both-sides rule: pre-swizzled global source slot +
// swizzled read chunk) turning the 8-way conflict into a free 2-way.
// LDS 44.5 KB -> 3 blocks/CU >= grid's 2. ----
__global__ __launch_bounds__(256) void mla_attn_kernel(
    const ushort_t* __restrict__ qb, const ushort_t* __restrict__ kvb,
    const ushort_t* __restrict__ kpe, const ushort_t* __restrict__ v16t,
    ushort_t* __restrict__ aout16)
{
    __shared__ ushort_t Kn[2][4 * 32 * 32];   // 16 KB (2 buf x 128 dims x 32 keys)
    __shared__ ushort_t Kr[2][2 * 32 * 32];   //  8 KB
    __shared__ ushort_t Vt[2][128 * 32];      // 16 KB (dv x keys)
    __shared__ ushort_t Ps[4][16 * 36];       //  4.5 KB (per-wave P, conflict-free stride 36)

    const int h = blockIdx.x;
    const int q0 = 64 * (31 - blockIdx.y);  // heavy-first
    const int w = threadIdx.x >> 6;         // 0..3
    const int lane = threadIdx.x & 63;
    const int lm = lane & 15, quad = lane >> 4;
    const int qw = q0 + 16 * w;
    ushort_t* myPs = Ps[w];

    // staging lane decomposition: 16 rows x 4 slots of 16B, slot XOR-swizzled
    const int srow = lane >> 2;                               // 0..15
    const int ssw  = ((lane & 3) ^ ((lane >> 3) & 3)) * 8;    // swizzled slot (ushorts)
    // read-side swizzle: global chunk `quad` of row r lives at slot quad^((r>>1)&3);
    // all our rows r == lm (mod 16-aligned offsets), so:
    const int swq  = quad ^ ((lm >> 1) & 3);

    // Q fragments (un-roped source) + fused RoPE on chunks 4/5
    short8 qf[6];
    #pragma unroll
    for (int f = 0; f < 6; ++f)
        qf[f] = *(const short8*)(qb + (size_t)(qw + lm) * 3072 + h * 192 + f * 32 + quad * 8);
    {
        float srowf = (float)(qw + lm);
        #pragma unroll
        for (int j = 0; j < 8; ++j) {
            int i = quad * 8 + j;
            float inv = powf(10000.0f, -(2.0f * i) / 64.0f);
            float ang = srowf * inv;
            float c = cosf(ang), sn = sinf(ang);
            float x1 = bf2f((ushort_t)qf[4][j]);
            float x2 = bf2f((ushort_t)qf[5][j]);
            qf[4][j] = (short)f2bf(x1 * c - x2 * sn);
            qf[5][j] = (short)f2bf(x2 * c + x1 * sn);
        }
    }
    // drain Q loads so vmcnt bookkeeping below is exact
    asm volatile("s_waitcnt vmcnt(0)" ::: "memory");

    f32x4 O[8];
    #pragma unroll
    for (int c = 0; c < 8; ++c) O[c] = (f32x4){0.f, 0.f, 0.f, 0.f};
    float m_[4] = {-1e30f, -1e30f, -1e30f, -1e30f};
    float l_[4] = {0.f, 0.f, 0.f, 0.f};

    const ushort_t* kn_g = kvb + (size_t)h * 256;
    const ushort_t* vt_g = v16t + (size_t)h * 128 * S_LEN;

    // 5 global_load_lds per wave per tile (whole block stages the 32-key tile)
    auto stage = [&](int buf, int k0s) {
        // K-nope: this wave stages dim-chunk f = w, both 16-row halves
        #pragma unroll
        for (int i = 0; i < 2; ++i)
            gload_lds16(kn_g + (size_t)(k0s + i * 16 + srow) * 4096 + w * 32 + ssw,
                        &Kn[buf][w * 1024 + i * 512 + lane * 8]);
        // K-rope: wave w stages (f2 = w>>1, half i = w&1)
        gload_lds16(kpe + (size_t)(k0s + (w & 1) * 16 + srow) * 64 + (w >> 1) * 32 + ssw,
                    &Kr[buf][(w >> 1) * 1024 + (w & 1) * 512 + lane * 8]);
        // V^T: wave w stages dv rows j*16..j*16+15 for j = 2w, 2w+1
        #pragma unroll
        for (int jj = 0; jj < 2; ++jj) {
            int j = 2 * w + jj;
            gload_lds16(vt_g + (size_t)(j * 16 + srow) * S_LEN + k0s + ssw,
                        &Vt[buf][j * 512 + lane * 8]);
        }
    };

    const int nt = q0 / 32 + 2;   // keys 0 .. q0+64
    stage(0, 0);

    for (int t = 0; t < nt; ++t) {
        const int k0 = t * 32;
        if (t + 1 < nt) {
            stage((t + 1) & 1, k0 + 32);
            asm volatile("s_waitcnt vmcnt(5)" ::: "memory");  // tile t's 5 loads done; t+1's in flight
        } else {
            asm volatile("s_waitcnt vmcnt(0)" ::: "memory");
        }
        __builtin_amdgcn_s_barrier();
        __builtin_amdgcn_sched_barrier(0);

        if (k0 < qw + 16) {   // wave-uniform causal skip
            const ushort_t* KnB = Kn[t & 1];
            const ushort_t* KrB = Kr[t & 1];
            const ushort_t* VtB = Vt[t & 1];

            f32x4 s[2];
            s[0] = (f32x4){0.f, 0.f, 0.f, 0.f};
            s[1] = (f32x4){0.f, 0.f, 0.f, 0.f};
            #pragma unroll
            for (int st = 0; st < 2; ++st) {
                const int kl = st * 16 + lm;
                #pragma unroll
                for (int f = 0; f < 4; ++f) {
                    short8 kf = *(const short8*)(KnB + f * 1024 + kl * 32 + swq * 8);
                    s[st] = __builtin_amdgcn_mfma_f32_16x16x32_bf16(qf[f], kf, s[st], 0, 0, 0);
                }
                #pragma unroll
                for (int f2 = 0; f2 < 2; ++f2) {
                    short8 kr = *(const short8*)(KrB + f2 * 1024 + kl * 32 + swq * 8);
                    s[st] = __builtin_amdgcn_mfma_f32_16x16x32_bf16(qf[4 + f2], kr, s[st], 0, 0, 0);
                }
            }

            softmax_step32(s, k0, qw, lm, quad, m_, l_, O, myPs);

            asm volatile("s_waitcnt lgkmcnt(0)" ::: "memory");
            short8 pf = *(const short8*)(myPs + lm * 36 + quad * 8);
            #pragma unroll
            for (int c = 0; c < 8; ++c) {
                short8 vf = *(const short8*)(VtB + (c * 16 + lm) * 32 + swq * 8);
                O[c] = __builtin_amdgcn_mfma_f32_16x16x32_bf16(pf, vf, O[c], 0, 0, 0);
            }
        }
        __builtin_amdgcn_sched_barrier(0);
        __builtin_amdgcn_s_barrier();   // protect buf (t&1) from next iter's prefetch overwrite
    }

    // epilogue
    #pragma unroll
    for (int c = 0; c < 8; ++c)
        #pragma unroll
        for (int r = 0; r < 4; ++r) {
            int qrow = qw + quad * 4 + r;
            aout16[(size_t)qrow * 2048 + h * D_V + c * 16 + lm] = f2bf(O[c][r] / l_[r]);
        }
}

extern "C" void kernel_launch(void* const* d_in, const int* in_sizes, int n_in,
                              void* d_out, int out_size, void* d_ws, size_t ws_size,
                              hipStream_t stream)
{
    (void)in_sizes; (void)n_in; (void)out_size; (void)ws_size;
    const float* hs   = (const float*)d_in[0];
    const float* Wqa  = (const float*)d_in[1];
    const float* qlnw = (const float*)d_in[2];
    const float* Wqb  = (const float*)d_in[3];
    const float* Wkva = (const float*)d_in[4];
    const float* klnw = (const float*)d_in[5];
    const float* Wkvb = (const float*)d_in[6];
    const float* Wo   = (const float*)d_in[7];
    float* out = (float*)d_out;

    ushort_t* p = (ushort_t*)d_ws;
    ushort_t* hs16   = p; p += (size_t)S_LEN * H_DIM;
    ushort_t* WcatT  = p; p += (size_t)2176 * H_DIM;     // [Wqa^T 1536 ; Wkva^T 640] x 2048
    ushort_t* WqbT   = p; p += (size_t)3072 * Q_LORA;
    ushort_t* WkvbT  = p; p += (size_t)4096 * KV_LORA;
    ushort_t* WoT    = p; p += (size_t)H_DIM * H_DIM;
    ushort_t* cat16r = p; p += (size_t)S_LEN * 2176;     // [qa_raw | ckv_raw | kpe_raw | pad]
    ushort_t* qa16   = p; p += (size_t)S_LEN * Q_LORA;
    ushort_t* qbuf16 = p; p += (size_t)S_LEN * 3072;
    ushort_t* ckv16n = p; p += (size_t)S_LEN * KV_LORA;
    ushort_t* kpe16  = p; p += (size_t)S_LEN * D_ROPE;
    ushort_t* kv16   = p; p += (size_t)S_LEN * 4096;
    ushort_t* v16t   = p; p += (size_t)NH * D_V * S_LEN;
    ushort_t* aout16 = p; p += (size_t)S_LEN * 2048;

    // 1. all conversions in one launch (hs + 5 weight transposes)
    unified_conv<<<19200, 256, 0, stream>>>(
        hs, hs16, Wqa, Wkva, Wqb, Wkvb, Wo, WcatT, WqbT, WkvbT, WoT);
    // 2. cat16r = hs16 @ WcatT^T  [2048 x 2176, K=2048]  (fused Wqa + Wkva)
    mfma_gemm_bt<ushort_t><<<dim3(2176 / 128, S_LEN / 64), 256, 0, stream>>>(
        hs16, WcatT, cat16r, 2176, H_DIM);
    // 3. fused rmsnorm-q / rmsnorm-kv / rope-k
    fused_norm_ropek<<<4096 + 256, 256, 0, stream>>>(cat16r, qa16, ckv16n, kpe16, qlnw, klnw);
    // 4. grouped GEMM: qbuf16 = qa16 @ WqbT^T [2048x3072,K=1536] + kv16 = ckv16n @ WkvbT^T [2048x4096,K=512]
    mfma_gemm_dual<<<768 + 1024, 256, 0, stream>>>(
        qa16, WqbT, qbuf16, 3072, Q_LORA, 768,
        ckv16n, WkvbT, kv16, 4096, KV_LORA);
    // 5. V transpose
    conv_vT_kernel<<<dim3(S_LEN / 32, D_V / 32, NH), 256, 0, stream>>>(kv16, v16t);
    // 6. attention (pipelined KVBLK=32 double-buffer, 4-wave blocks, swizzled)
    mla_attn_kernel<<<dim3(NH, 32), 256, 0, stream>>>(qbuf16, kv16, kpe16, v16t, aout16);
    // 7. out = aout16 @ WoT^T [2048 x 2048, K=2048], fp32 store
    mfma_gemm_bt<float><<<dim3(H_DIM / 128, S_LEN / 64), 256, 0, stream>>>(
        aout16, WoT, out, H_DIM, H_DIM);
}

// Round 3
// 347.478 us; speedup vs baseline: 1.3772x; 1.0413x over previous
//
#include <hip/hip_runtime.h>
#include <hip/hip_bf16.h>
#include <math.h>

#define S_LEN 2048
#define H_DIM 2048
#define NH 16
#define Q_LORA 1536
#define KV_LORA 512
#define D_NOPE 128
#define D_ROPE 64
#define D_V 128
#define D_QK 192

typedef unsigned short ushort_t;
typedef __attribute__((ext_vector_type(8))) short short8;
typedef __attribute__((ext_vector_type(4))) float f32x4;

__device__ __forceinline__ ushort_t f2bf(float f) {
    unsigned int u = __float_as_uint(f);
    u = (u + 0x7FFFu + ((u >> 16) & 1u)) >> 16;
    return (ushort_t)u;
}
__device__ __forceinline__ float bf2f(ushort_t u) {
    return __uint_as_float(((unsigned int)u) << 16);
}

__device__ __forceinline__ void storeC(float* p, float v) { *p = v; }
__device__ __forceinline__ void storeC(ushort_t* p, float v) { *p = f2bf(v); }

__device__ __forceinline__ void gload_lds16(const ushort_t* g, ushort_t* l) {
    __builtin_amdgcn_global_load_lds(
        (const __attribute__((address_space(1))) unsigned int*)(const void*)g,
        (__attribute__((address_space(3))) unsigned int*)(void*)l, 16, 0, 0);
}

// 16-lane DPP-row reductions (pure VALU)
__device__ __forceinline__ float dpp_max16(float x) {
    x = fmaxf(x, __int_as_float(__builtin_amdgcn_update_dpp(0, __float_as_int(x), 0xB1, 0xF, 0xF, true)));
    x = fmaxf(x, __int_as_float(__builtin_amdgcn_update_dpp(0, __float_as_int(x), 0x4E, 0xF, 0xF, true)));
    x = fmaxf(x, __int_as_float(__builtin_amdgcn_update_dpp(0, __float_as_int(x), 0x124, 0xF, 0xF, true)));
    x = fmaxf(x, __int_as_float(__builtin_amdgcn_update_dpp(0, __float_as_int(x), 0x128, 0xF, 0xF, true)));
    return x;
}
__device__ __forceinline__ float dpp_sum16(float x) {
    x += __int_as_float(__builtin_amdgcn_update_dpp(0, __float_as_int(x), 0xB1, 0xF, 0xF, true));
    x += __int_as_float(__builtin_amdgcn_update_dpp(0, __float_as_int(x), 0x4E, 0xF, 0xF, true));
    x += __int_as_float(__builtin_amdgcn_update_dpp(0, __float_as_int(x), 0x124, 0xF, 0xF, true));
    x += __int_as_float(__builtin_amdgcn_update_dpp(0, __float_as_int(x), 0x128, 0xF, 0xF, true));
    return x;
}

// -------- unified conversion: hs f32->bf16 + 5 weight transposes, one launch --------
__device__ __forceinline__ void convT_body(
    const float* __restrict__ W, ushort_t* __restrict__ Wt,
    int K, int N, int n0, int k0, float (*tile)[33])
{
    const int tr = threadIdx.x >> 5, tc = threadIdx.x & 31;
    #pragma unroll
    for (int i = 0; i < 4; ++i) {
        int r = tr + i * 8;
        float v = 0.f;
        if (n0 + tc < N) v = W[(size_t)(k0 + r) * N + n0 + tc];
        tile[r][tc] = v;
    }
    __syncthreads();
    #pragma unroll
    for (int i = 0; i < 4; ++i) {
        int r = tr + i * 8;
        Wt[(size_t)(n0 + r) * K + k0 + tc] = f2bf(tile[tc][r]);
    }
}

__global__ __launch_bounds__(256) void unified_conv(
    const float* __restrict__ hs, ushort_t* __restrict__ hs16,
    const float* __restrict__ Wqa, const float* __restrict__ Wkva,
    const float* __restrict__ Wqb, const float* __restrict__ Wkvb,
    const float* __restrict__ Wo,
    ushort_t* __restrict__ WcatT, ushort_t* __restrict__ WqbT,
    ushort_t* __restrict__ WkvbT, ushort_t* __restrict__ WoT)
{
    __shared__ float tile[32][33];
    int b = blockIdx.x;
    if (b < 4096) {   // hs elementwise
        int base = (b * 256 + threadIdx.x) * 4;
        float4 v = *(const float4*)(hs + base);
        hs16[base + 0] = f2bf(v.x);
        hs16[base + 1] = f2bf(v.y);
        hs16[base + 2] = f2bf(v.z);
        hs16[base + 3] = f2bf(v.w);
        return;
    }
    b -= 4096;
    const float* W; ushort_t* Wt; int K, N, nbx;
    if (b < 3072)        {            W = Wqa;  Wt = WcatT;                              K = 2048; N = 1536; nbx = 48;  }
    else if (b < 4352)   { b -= 3072; W = Wkva; Wt = WcatT + (size_t)Q_LORA * H_DIM;     K = 2048; N = 576;  nbx = 20;  }
    else if (b < 8960)   { b -= 4352; W = Wqb;  Wt = WqbT;                               K = 1536; N = 3072; nbx = 96;  }
    else if (b < 11008)  { b -= 8960; W = Wkvb; Wt = WkvbT;                              K = 512;  N = 4096; nbx = 128; }
    else                 { b -= 11008; W = Wo;  Wt = WoT;                                K = 2048; N = 2048; nbx = 64;  }
    convT_body(W, Wt, K, N, (b % nbx) * 32, (b / nbx) * 32, tile);
}

// ------- fused: rmsnorm-q (blocks 0..2047) + rmsnorm-kv (2048..4095) + rope-k (4096..) -------
__global__ __launch_bounds__(256) void fused_norm_ropek(
    const ushort_t* __restrict__ cat16r, ushort_t* __restrict__ qa16,
    ushort_t* __restrict__ ckv16n, ushort_t* __restrict__ kpe16,
    const float* __restrict__ qlnw, const float* __restrict__ klnw)
{
    __shared__ float red[4];
    const int b = blockIdx.x;
    if (b < 4096) {
        const bool isQ = (b < 2048);
        const int row = isQ ? b : b - 2048;
        const int K = isQ ? Q_LORA : KV_LORA;
        const ushort_t* x = cat16r + (size_t)row * 2176 + (isQ ? 0 : Q_LORA);
        ushort_t* y = (isQ ? qa16 + (size_t)row * Q_LORA : ckv16n + (size_t)row * KV_LORA);
        const float* wv = isQ ? qlnw : klnw;
        float ss = 0.f;
        for (int i = threadIdx.x; i < K; i += 256) { float v = bf2f(x[i]); ss += v * v; }
        #pragma unroll
        for (int off = 32; off > 0; off >>= 1) ss += __shfl_down(ss, off);
        int lane = threadIdx.x & 63, wid = threadIdx.x >> 6;
        if (lane == 0) red[wid] = ss;
        __syncthreads();
        float tot = red[0] + red[1] + red[2] + red[3];
        float rs = rsqrtf(tot / (float)K + 1e-6f);
        for (int i = threadIdx.x; i < K; i += 256)
            y[i] = f2bf(bf2f(x[i]) * rs * wv[i]);
    } else {
        int idx = (b - 4096) * 256 + threadIdx.x;
        if (idx >= S_LEN * 32) return;
        int i = idx & 31;
        int s = idx >> 5;
        float inv = powf(10000.0f, -(2.0f * i) / 64.0f);
        float ang = (float)s * inv;
        float c = cosf(ang), sn = sinf(ang);
        const ushort_t* p = cat16r + (size_t)s * 2176 + Q_LORA + KV_LORA;
        ushort_t* q = kpe16 + (size_t)s * D_ROPE;
        float x1 = bf2f(p[i]), x2 = bf2f(p[i + 32]);
        q[i]      = f2bf(x1 * c - x2 * sn);
        q[i + 32] = f2bf(x2 * c + x1 * sn);
    }
}

// ---------------- V transpose: kv16[s][h*256+128+dv] -> v16t[h][dv][s] ----------------
__global__ __launch_bounds__(256) void conv_vT_kernel(
    const ushort_t* __restrict__ kv, ushort_t* __restrict__ v16t)
{
    __shared__ ushort_t tile[32][33];
    const int h = blockIdx.z;
    const int s0 = blockIdx.x * 32, d0 = blockIdx.y * 32;
    const int tr = threadIdx.x >> 5, tc = threadIdx.x & 31;
    #pragma unroll
    for (int i = 0; i < 4; ++i) {
        int r = tr + i * 8;  // s
        tile[r][tc] = kv[(size_t)(s0 + r) * 4096 + h * 256 + D_NOPE + d0 + tc];
    }
    __syncthreads();
    #pragma unroll
    for (int i = 0; i < 4; ++i) {
        int r = tr + i * 8;  // dv
        v16t[(size_t)h * D_V * S_LEN + (size_t)(d0 + r) * S_LEN + s0 + tc] = tile[tc][r];
    }
}

// ---- MFMA GEMM body, 128x128 tile (m97 structure), 4 waves in 2x2, acc[4][4],
// BK=64 (two 32-chunks per barrier). LDS 32 KB -> 4 blocks/CU. ----
template <typename CT>
__device__ __forceinline__ void gemm_body_128(
    const ushort_t* __restrict__ A, const ushort_t* __restrict__ Bt,
    CT* __restrict__ C, int N, int K, int m0, int n0,
    ushort_t* Al, ushort_t* Bl)  // each 2 * 128 * 32 ushorts = 16 KB
{
    const int tid = threadIdx.x;
    const int lane = tid & 63;
    const int w = tid >> 6;
    const int lm = lane & 15, quad = lane >> 4;
    const int wr = w >> 1, wc = w & 1;

    f32x4 acc[4][4];
    #pragma unroll
    for (int a = 0; a < 4; ++a)
        #pragma unroll
        for (int b = 0; b < 4; ++b) acc[a][b] = (f32x4){0.f, 0.f, 0.f, 0.f};

    const int rrow = tid >> 2;        // 0..63
    const int rcol = (tid & 3) * 8;   // 0,8,16,24

    for (int k0 = 0; k0 < K; k0 += 64) {
        __syncthreads();
        #pragma unroll
        for (int c = 0; c < 2; ++c)
            #pragma unroll
            for (int half = 0; half < 2; ++half) {
                gload_lds16(A + (size_t)(m0 + half * 64 + rrow) * K + k0 + c * 32 + rcol,
                            Al + c * 4096 + half * 2048 + tid * 8);
                gload_lds16(Bt + (size_t)(n0 + half * 64 + rrow) * K + k0 + c * 32 + rcol,
                            Bl + c * 4096 + half * 2048 + tid * 8);
            }
        __syncthreads();

        #pragma unroll
        for (int c = 0; c < 2; ++c) {
            short8 af[4], bf[4];
            #pragma unroll
            for (int t = 0; t < 4; ++t)
                af[t] = *(const short8*)(Al + c * 4096 + (wr * 64 + t * 16 + lm) * 32 + quad * 8);
            #pragma unroll
            for (int t = 0; t < 4; ++t)
                bf[t] = *(const short8*)(Bl + c * 4096 + (wc * 64 + t * 16 + lm) * 32 + quad * 8);
            #pragma unroll
            for (int mt = 0; mt < 4; ++mt)
                #pragma unroll
                for (int nt = 0; nt < 4; ++nt)
                    acc[mt][nt] = __builtin_amdgcn_mfma_f32_16x16x32_bf16(
                        af[mt], bf[nt], acc[mt][nt], 0, 0, 0);
        }
    }

    #pragma unroll
    for (int mt = 0; mt < 4; ++mt)
        #pragma unroll
        for (int nt = 0; nt < 4; ++nt)
            #pragma unroll
            for (int r = 0; r < 4; ++r) {
                int row = m0 + wr * 64 + mt * 16 + quad * 4 + r;
                int col = n0 + wc * 64 + nt * 16 + lm;
                storeC(&C[(size_t)row * N + col], acc[mt][nt][r]);
            }
}

template <typename CT>
__global__ __launch_bounds__(256) void mfma_gemm_bt(
    const ushort_t* __restrict__ A, const ushort_t* __restrict__ Bt,
    CT* __restrict__ C, int N, int K)
{
    __shared__ ushort_t Al[2 * 128 * 32];
    __shared__ ushort_t Bl[2 * 128 * 32];
    gemm_body_128<CT>(A, Bt, C, N, K, blockIdx.y * 128, blockIdx.x * 128, Al, Bl);
}

__global__ __launch_bounds__(256) void mfma_gemm_dual(
    const ushort_t* __restrict__ A1, const ushort_t* __restrict__ Bt1,
    ushort_t* __restrict__ C1, int N1, int K1, int nb1,
    const ushort_t* __restrict__ A2, const ushort_t* __restrict__ Bt2,
    ushort_t* __restrict__ C2, int N2, int K2)
{
    __shared__ ushort_t Al[2 * 128 * 32];
    __shared__ ushort_t Bl[2 * 128 * 32];
    int g = blockIdx.x;
    if (g < nb1) {
        int nbx = N1 / 128;
        gemm_body_128<ushort_t>(A1, Bt1, C1, N1, K1, (g / nbx) * 128, (g % nbx) * 128, Al, Bl);
    } else {
        g -= nb1;
        int nbx = N2 / 128;
        gemm_body_128<ushort_t>(A2, Bt2, C2, N2, K2, (g / nbx) * 128, (g % nbx) * 128, Al, Bl);
    }
}

// online-softmax update for one 16x64 score tile in C layout (DPP); P -> ps[16][72]
__device__ __forceinline__ void softmax_step(
    f32x4 s[4], int k0, int qw, int lm, int quad,
    float m_[4], float l_[4], f32x4 O[8], ushort_t* ps)
{
    const float scale = 0.07216878364870322f;  // 192^-0.5
    #pragma unroll
    for (int r = 0; r < 4; ++r) {
        int qrow = qw + quad * 4 + r;
        float a[4];
        #pragma unroll
        for (int st = 0; st < 4; ++st)
            a[st] = (k0 + st * 16 + lm <= qrow) ? s[st][r] * scale : -1e30f;
        float mx = dpp_max16(fmaxf(fmaxf(a[0], a[1]), fmaxf(a[2], a[3])));
        float mn = fmaxf(m_[r], mx);
        float p[4];
        #pragma unroll
        for (int st = 0; st < 4; ++st) p[st] = __expf(a[st] - mn);
        float alpha = __expf(m_[r] - mn);
        float psum = dpp_sum16((p[0] + p[1]) + (p[2] + p[3]));
        l_[r] = l_[r] * alpha + psum;
        m_[r] = mn;
        #pragma unroll
        for (int c = 0; c < 8; ++c) O[c][r] *= alpha;
        #pragma unroll
        for (int st = 0; st < 4; ++st)
            ps[(quad * 4 + r) * 72 + st * 16 + lm] = f2bf(p[st]);
    }
}

// ---- MFMA flash attention: round-0 structure (best anchor, 86.8 µs) +
// validated XOR bank-swizzle on staging/read (round-2: conflicts 5.68M -> 0)
// + T5 setprio around MFMA clusters. KVBLK=64, 2-wave blocks, heavy-first. ----
__global__ __launch_bounds__(128) void mla_attn_kernel(
    const ushort_t* __restrict__ qb, const ushort_t* __restrict__ kvb,
    const ushort_t* __restrict__ kpe, const ushort_t* __restrict__ v16t,
    ushort_t* __restrict__ aout16)
{
    __shared__ ushort_t Kn[4 * 64 * 32];   // 16 KB
    __shared__ ushort_t Kr[2 * 64 * 32];   //  8 KB
    __shared__ ushort_t Vt[2 * 128 * 32];  // 16 KB
    __shared__ ushort_t Ps[2][16][72];     // 4.5 KB

    const int h = blockIdx.x;
    const int q0 = 32 * (63 - blockIdx.y);  // heavy-first
    const int w = threadIdx.x >> 6;         // 0..1
    const int lane = threadIdx.x & 63;
    const int lm = lane & 15, quad = lane >> 4;
    const int qw = q0 + 16 * w;
    ushort_t* myPs = &Ps[w][0][0];

    // staging swizzle (validated round 2): LDS row r slot s holds global chunk
    // s ^ ((r>>1)&3); row = lane>>2, source slot = (lane&3)^((lane>>3)&3)
    const int skey = lane >> 2;                               // 0..15
    const int ssw  = ((lane & 3) ^ ((lane >> 3) & 3)) * 8;    // swizzled source slot
    const int swq  = quad ^ ((lm >> 1) & 3);                  // swizzled read slot

    // Q fragments (un-roped source) + fused RoPE on chunks 4/5
    short8 qf[6];
    #pragma unroll
    for (int f = 0; f < 6; ++f)
        qf[f] = *(const short8*)(qb + (size_t)(qw + lm) * 3072 + h * 192 + f * 32 + quad * 8);
    {
        float srow = (float)(qw + lm);
        #pragma unroll
        for (int j = 0; j < 8; ++j) {
            int i = quad * 8 + j;
            float inv = powf(10000.0f, -(2.0f * i) / 64.0f);
            float ang = srow * inv;
            float c = cosf(ang), sn = sinf(ang);
            float x1 = bf2f((ushort_t)qf[4][j]);
            float x2 = bf2f((ushort_t)qf[5][j]);
            qf[4][j] = (short)f2bf(x1 * c - x2 * sn);
            qf[5][j] = (short)f2bf(x2 * c + x1 * sn);
        }
    }

    f32x4 O[8];
    #pragma unroll
    for (int c = 0; c < 8; ++c) O[c] = (f32x4){0.f, 0.f, 0.f, 0.f};
    float m_[4] = {-1e30f, -1e30f, -1e30f, -1e30f};
    float l_[4] = {0.f, 0.f, 0.f, 0.f};

    const int kend = q0 + 32;
    for (int k0 = 0; k0 < kend; k0 += 64) {
        __syncthreads();
        {
            // K-nope: wave w covers f in {2w, 2w+1}, i = 0..3 (8 instr/wave)
            #pragma unroll
            for (int fi = 0; fi < 2; ++fi) {
                int f = 2 * w + fi;
                #pragma unroll
                for (int i = 0; i < 4; ++i)
                    gload_lds16(kvb + (size_t)(k0 + i * 16 + skey) * 4096 + h * 256 + f * 32 + ssw,
                                Kn + f * 2048 + i * 512 + lane * 8);
            }
            // K-rope: f2 = w, i = 0..3 (4 instr/wave)
            #pragma unroll
            for (int i = 0; i < 4; ++i)
                gload_lds16(kpe + (size_t)(k0 + i * 16 + skey) * 64 + w * 32 + ssw,
                            Kr + w * 2048 + i * 512 + lane * 8);
            // V^T: half = w, j = 0..7 (8 instr/wave)
            #pragma unroll
            for (int j = 0; j < 8; ++j)
                gload_lds16(v16t + ((size_t)h * 128 + j * 16 + skey) * S_LEN + k0 + w * 32 + ssw,
                            Vt + w * 4096 + j * 512 + lane * 8);
        }
        __syncthreads();

        if (k0 < qw + 16) {  // wave-uniform causal skip (wave 1 always active)
            f32x4 s[4];
            #pragma unroll
            for (int st = 0; st < 4; ++st) s[st] = (f32x4){0.f, 0.f, 0.f, 0.f};
            __builtin_amdgcn_s_setprio(1);
            #pragma unroll
            for (int f = 0; f < 4; ++f)
                #pragma unroll
                for (int st = 0; st < 4; ++st) {
                    short8 kf = *(const short8*)(Kn + f * 2048 + (st * 16 + lm) * 32 + swq * 8);
                    s[st] = __builtin_amdgcn_mfma_f32_16x16x32_bf16(qf[f], kf, s[st], 0, 0, 0);
                }
            #pragma unroll
            for (int f2 = 0; f2 < 2; ++f2)
                #pragma unroll
                for (int st = 0; st < 4; ++st) {
                    short8 kf = *(const short8*)(Kr + f2 * 2048 + (st * 16 + lm) * 32 + swq * 8);
                    s[st] = __builtin_amdgcn_mfma_f32_16x16x32_bf16(qf[4 + f2], kf, s[st], 0, 0, 0);
                }
            __builtin_amdgcn_s_setprio(0);

            softmax_step(s, k0, qw, lm, quad, m_, l_, O, myPs);

            asm volatile("s_waitcnt lgkmcnt(0)" ::: "memory");
            short8 pf0 = *(const short8*)(myPs + lm * 72 + quad * 8);
            short8 pf1 = *(const short8*)(myPs + lm * 72 + 32 + quad * 8);
            __builtin_amdgcn_s_setprio(1);
            #pragma unroll
            for (int c = 0; c < 8; ++c) {
                short8 vf0 = *(const short8*)(Vt + (c * 16 + lm) * 32 + swq * 8);
                short8 vf1 = *(const short8*)(Vt + 4096 + (c * 16 + lm) * 32 + swq * 8);
                O[c] = __builtin_amdgcn_mfma_f32_16x16x32_bf16(pf0, vf0, O[c], 0, 0, 0);
                O[c] = __builtin_amdgcn_mfma_f32_16x16x32_bf16(pf1, vf1, O[c], 0, 0, 0);
            }
            __builtin_amdgcn_s_setprio(0);
        }
    }
    // epilogue
    #pragma unroll
    for (int c = 0; c < 8; ++c)
        #pragma unroll
        for (int r = 0; r < 4; ++r) {
            int qrow = qw + quad * 4 + r;
            aout16[(size_t)qrow * 2048 + h * D_V + c * 16 + lm] = f2bf(O[c][r] / l_[r]);
        }
}

extern "C" void kernel_launch(void* const* d_in, const int* in_sizes, int n_in,
                              void* d_out, int out_size, void* d_ws, size_t ws_size,
                              hipStream_t stream)
{
    (void)in_sizes; (void)n_in; (void)out_size; (void)ws_size;
    const float* hs   = (const float*)d_in[0];
    const float* Wqa  = (const float*)d_in[1];
    const float* qlnw = (const float*)d_in[2];
    const float* Wqb  = (const float*)d_in[3];
    const float* Wkva = (const float*)d_in[4];
    const float* klnw = (const float*)d_in[5];
    const float* Wkvb = (const float*)d_in[6];
    const float* Wo   = (const float*)d_in[7];
    float* out = (float*)d_out;

    ushort_t* p = (ushort_t*)d_ws;
    ushort_t* hs16   = p; p += (size_t)S_LEN * H_DIM;
    ushort_t* WcatT  = p; p += (size_t)2176 * H_DIM;     // [Wqa^T 1536 ; Wkva^T 640] x 2048
    ushort_t* WqbT   = p; p += (size_t)3072 * Q_LORA;
    ushort_t* WkvbT  = p; p += (size_t)4096 * KV_LORA;
    ushort_t* WoT    = p; p += (size_t)H_DIM * H_DIM;
    ushort_t* cat16r = p; p += (size_t)S_LEN * 2176;     // [qa_raw | ckv_raw | kpe_raw | pad]
    ushort_t* qa16   = p; p += (size_t)S_LEN * Q_LORA;
    ushort_t* qbuf16 = p; p += (size_t)S_LEN * 3072;
    ushort_t* ckv16n = p; p += (size_t)S_LEN * KV_LORA;
    ushort_t* kpe16  = p; p += (size_t)S_LEN * D_ROPE;
    ushort_t* kv16   = p; p += (size_t)S_LEN * 4096;
    ushort_t* v16t   = p; p += (size_t)NH * D_V * S_LEN;
    ushort_t* aout16 = p; p += (size_t)S_LEN * 2048;

    // 1. all conversions in one launch (hs + 5 weight transposes)
    unified_conv<<<19200, 256, 0, stream>>>(
        hs, hs16, Wqa, Wkva, Wqb, Wkvb, Wo, WcatT, WqbT, WkvbT, WoT);
    // 2. cat16r = hs16 @ WcatT^T  [2048 x 2176, K=2048]  (fused Wqa + Wkva)
    mfma_gemm_bt<ushort_t><<<dim3(2176 / 128, S_LEN / 128), 256, 0, stream>>>(
        hs16, WcatT, cat16r, 2176, H_DIM);
    // 3. fused rmsnorm-q / rmsnorm-kv / rope-k
    fused_norm_ropek<<<4096 + 256, 256, 0, stream>>>(cat16r, qa16, ckv16n, kpe16, qlnw, klnw);
    // 4. grouped GEMM: qbuf16 = qa16 @ WqbT^T [2048x3072,K=1536] + kv16 = ckv16n @ WkvbT^T [2048x4096,K=512]
    mfma_gemm_dual<<<384 + 512, 256, 0, stream>>>(
        qa16, WqbT, qbuf16, 3072, Q_LORA, 384,
        ckv16n, WkvbT, kv16, 4096, KV_LORA);
    // 5. V transpose
    conv_vT_kernel<<<dim3(S_LEN / 32, D_V / 32, NH), 256, 0, stream>>>(kv16, v16t);
    // 6. attention (round-0 staging + swizzle + setprio)
    mla_attn_kernel<<<dim3(NH, 64), 128, 0, stream>>>(qbuf16, kv16, kpe16, v16t, aout16);
    // 7. out = aout16 @ WoT^T [2048 x 2048, K=2048], fp32 store
    mfma_gemm_bt<float><<<dim3(H_DIM / 128, S_LEN / 128), 256, 0, stream>>>(
        aout16, WoT, out, H_DIM, H_DIM);
}

// Round 4
// 340.561 us; speedup vs baseline: 1.4052x; 1.0203x over previous
//
#include <hip/hip_runtime.h>
#include <hip/hip_bf16.h>
#include <math.h>

#define S_LEN 2048
#define H_DIM 2048
#define NH 16
#define Q_LORA 1536
#define KV_LORA 512
#define D_NOPE 128
#define D_ROPE 64
#define D_V 128
#define D_QK 192

typedef unsigned short ushort_t;
typedef __attribute__((ext_vector_type(8))) short short8;
typedef __attribute__((ext_vector_type(4))) float f32x4;

__device__ __forceinline__ ushort_t f2bf(float f) {
    unsigned int u = __float_as_uint(f);
    u = (u + 0x7FFFu + ((u >> 16) & 1u)) >> 16;
    return (ushort_t)u;
}
__device__ __forceinline__ float bf2f(ushort_t u) {
    return __uint_as_float(((unsigned int)u) << 16);
}

__device__ __forceinline__ void storeC(float* p, float v) { *p = v; }
__device__ __forceinline__ void storeC(ushort_t* p, float v) { *p = f2bf(v); }

__device__ __forceinline__ void gload_lds16(const ushort_t* g, ushort_t* l) {
    __builtin_amdgcn_global_load_lds(
        (const __attribute__((address_space(1))) unsigned int*)(const void*)g,
        (__attribute__((address_space(3))) unsigned int*)(void*)l, 16, 0, 0);
}

// 16-lane DPP-row reductions (pure VALU)
__device__ __forceinline__ float dpp_max16(float x) {
    x = fmaxf(x, __int_as_float(__builtin_amdgcn_update_dpp(0, __float_as_int(x), 0xB1, 0xF, 0xF, true)));
    x = fmaxf(x, __int_as_float(__builtin_amdgcn_update_dpp(0, __float_as_int(x), 0x4E, 0xF, 0xF, true)));
    x = fmaxf(x, __int_as_float(__builtin_amdgcn_update_dpp(0, __float_as_int(x), 0x124, 0xF, 0xF, true)));
    x = fmaxf(x, __int_as_float(__builtin_amdgcn_update_dpp(0, __float_as_int(x), 0x128, 0xF, 0xF, true)));
    return x;
}
__device__ __forceinline__ float dpp_sum16(float x) {
    x += __int_as_float(__builtin_amdgcn_update_dpp(0, __float_as_int(x), 0xB1, 0xF, 0xF, true));
    x += __int_as_float(__builtin_amdgcn_update_dpp(0, __float_as_int(x), 0x4E, 0xF, 0xF, true));
    x += __int_as_float(__builtin_amdgcn_update_dpp(0, __float_as_int(x), 0x124, 0xF, 0xF, true));
    x += __int_as_float(__builtin_amdgcn_update_dpp(0, __float_as_int(x), 0x128, 0xF, 0xF, true));
    return x;
}

// -------- unified conversion: hs f32->bf16 + 5 weight transposes, one launch --------
__device__ __forceinline__ void convT_body(
    const float* __restrict__ W, ushort_t* __restrict__ Wt,
    int K, int N, int n0, int k0, float (*tile)[33])
{
    const int tr = threadIdx.x >> 5, tc = threadIdx.x & 31;
    #pragma unroll
    for (int i = 0; i < 4; ++i) {
        int r = tr + i * 8;
        float v = 0.f;
        if (n0 + tc < N) v = W[(size_t)(k0 + r) * N + n0 + tc];
        tile[r][tc] = v;
    }
    __syncthreads();
    #pragma unroll
    for (int i = 0; i < 4; ++i) {
        int r = tr + i * 8;
        Wt[(size_t)(n0 + r) * K + k0 + tc] = f2bf(tile[tc][r]);
    }
}

__global__ __launch_bounds__(256) void unified_conv(
    const float* __restrict__ hs, ushort_t* __restrict__ hs16,
    const float* __restrict__ Wqa, const float* __restrict__ Wkva,
    const float* __restrict__ Wqb, const float* __restrict__ Wkvb,
    const float* __restrict__ Wo,
    ushort_t* __restrict__ WcatT, ushort_t* __restrict__ WqbT,
    ushort_t* __restrict__ WkvbT, ushort_t* __restrict__ WoT)
{
    __shared__ float tile[32][33];
    int b = blockIdx.x;
    if (b < 4096) {   // hs elementwise
        int base = (b * 256 + threadIdx.x) * 4;
        float4 v = *(const float4*)(hs + base);
        hs16[base + 0] = f2bf(v.x);
        hs16[base + 1] = f2bf(v.y);
        hs16[base + 2] = f2bf(v.z);
        hs16[base + 3] = f2bf(v.w);
        return;
    }
    b -= 4096;
    const float* W; ushort_t* Wt; int K, N, nbx;
    if (b < 3072)        {            W = Wqa;  Wt = WcatT;                              K = 2048; N = 1536; nbx = 48;  }
    else if (b < 4352)   { b -= 3072; W = Wkva; Wt = WcatT + (size_t)Q_LORA * H_DIM;     K = 2048; N = 576;  nbx = 20;  }
    else if (b < 8960)   { b -= 4352; W = Wqb;  Wt = WqbT;                               K = 1536; N = 3072; nbx = 96;  }
    else if (b < 11008)  { b -= 8960; W = Wkvb; Wt = WkvbT;                              K = 512;  N = 4096; nbx = 128; }
    else                 { b -= 11008; W = Wo;  Wt = WoT;                                K = 2048; N = 2048; nbx = 64;  }
    convT_body(W, Wt, K, N, (b % nbx) * 32, (b / nbx) * 32, tile);
}

// ------- fused: rmsnorm-q (blocks 0..2047) + rmsnorm-kv (2048..4095) + rope-k (4096..) -------
__global__ __launch_bounds__(256) void fused_norm_ropek(
    const ushort_t* __restrict__ cat16r, ushort_t* __restrict__ qa16,
    ushort_t* __restrict__ ckv16n, ushort_t* __restrict__ kpe16,
    const float* __restrict__ qlnw, const float* __restrict__ klnw)
{
    __shared__ float red[4];
    const int b = blockIdx.x;
    if (b < 4096) {
        const bool isQ = (b < 2048);
        const int row = isQ ? b : b - 2048;
        const int K = isQ ? Q_LORA : KV_LORA;
        const ushort_t* x = cat16r + (size_t)row * 2176 + (isQ ? 0 : Q_LORA);
        ushort_t* y = (isQ ? qa16 + (size_t)row * Q_LORA : ckv16n + (size_t)row * KV_LORA);
        const float* wv = isQ ? qlnw : klnw;
        float ss = 0.f;
        for (int i = threadIdx.x; i < K; i += 256) { float v = bf2f(x[i]); ss += v * v; }
        #pragma unroll
        for (int off = 32; off > 0; off >>= 1) ss += __shfl_down(ss, off);
        int lane = threadIdx.x & 63, wid = threadIdx.x >> 6;
        if (lane == 0) red[wid] = ss;
        __syncthreads();
        float tot = red[0] + red[1] + red[2] + red[3];
        float rs = rsqrtf(tot / (float)K + 1e-6f);
        for (int i = threadIdx.x; i < K; i += 256)
            y[i] = f2bf(bf2f(x[i]) * rs * wv[i]);
    } else {
        int idx = (b - 4096) * 256 + threadIdx.x;
        if (idx >= S_LEN * 32) return;
        int i = idx & 31;
        int s = idx >> 5;
        float inv = powf(10000.0f, -(2.0f * i) / 64.0f);
        float ang = (float)s * inv;
        float c = cosf(ang), sn = sinf(ang);
        const ushort_t* p = cat16r + (size_t)s * 2176 + Q_LORA + KV_LORA;
        ushort_t* q = kpe16 + (size_t)s * D_ROPE;
        float x1 = bf2f(p[i]), x2 = bf2f(p[i + 32]);
        q[i]      = f2bf(x1 * c - x2 * sn);
        q[i + 32] = f2bf(x2 * c + x1 * sn);
    }
}

// ---------------- V transpose: kv16[s][h*256+128+dv] -> v16t[h][dv][s] ----------------
__global__ __launch_bounds__(256) void conv_vT_kernel(
    const ushort_t* __restrict__ kv, ushort_t* __restrict__ v16t)
{
    __shared__ ushort_t tile[32][33];
    const int h = blockIdx.z;
    const int s0 = blockIdx.x * 32, d0 = blockIdx.y * 32;
    const int tr = threadIdx.x >> 5, tc = threadIdx.x & 31;
    #pragma unroll
    for (int i = 0; i < 4; ++i) {
        int r = tr + i * 8;  // s
        tile[r][tc] = kv[(size_t)(s0 + r) * 4096 + h * 256 + D_NOPE + d0 + tc];
    }
    __syncthreads();
    #pragma unroll
    for (int i = 0; i < 4; ++i) {
        int r = tr + i * 8;  // dv
        v16t[(size_t)h * D_V * S_LEN + (size_t)(d0 + r) * S_LEN + s0 + tc] = tile[tc][r];
    }
}

// ---- MFMA GEMM body, 128x128 tile, 4 waves 2x2, acc[4][4], BK=64.
// PIPELINED (T3 minimum 2-phase): double-buffered LDS (64 KB), next tile's
// global_load_lds issued BEFORE computing current tile, ONE vmcnt(0)+barrier
// per K-step at the END -> staging latency hides under the 32-MFMA compute.
// Needed because grids here are ~1 block/CU (no cross-block overlap).
// + XOR bank-swizzle on staging source slot / read slot (R2-validated):
// LDS row r, slot s holds global chunk s ^ ((r>>1)&3). ----
template <typename CT>
__device__ __forceinline__ void gemm_body_128(
    const ushort_t* __restrict__ A, const ushort_t* __restrict__ Bt,
    CT* __restrict__ C, int N, int K, int m0, int n0,
    ushort_t* Al, ushort_t* Bl)  // each 2 bufs * 8192 ushorts = 32 KB
{
    const int tid = threadIdx.x;
    const int lane = tid & 63;
    const int w = tid >> 6;
    const int lm = lane & 15, quad = lane >> 4;
    const int wr = w >> 1, wc = w & 1;

    f32x4 acc[4][4];
    #pragma unroll
    for (int a = 0; a < 4; ++a)
        #pragma unroll
        for (int b = 0; b < 4; ++b) acc[a][b] = (f32x4){0.f, 0.f, 0.f, 0.f};

    const int rrow = tid >> 2;                                // 0..63
    const int rcsw = ((tid & 3) ^ ((tid >> 3) & 3)) * 8;      // swizzled source k-slot
    const int swq  = quad ^ ((lm >> 1) & 3);                  // swizzled read slot

    const int NT = K >> 6;

    auto stage = [&](int buf, int k0) {
        #pragma unroll
        for (int c = 0; c < 2; ++c)
            #pragma unroll
            for (int half = 0; half < 2; ++half) {
                gload_lds16(A + (size_t)(m0 + half * 64 + rrow) * K + k0 + c * 32 + rcsw,
                            Al + buf * 8192 + c * 4096 + half * 2048 + tid * 8);
                gload_lds16(Bt + (size_t)(n0 + half * 64 + rrow) * K + k0 + c * 32 + rcsw,
                            Bl + buf * 8192 + c * 4096 + half * 2048 + tid * 8);
            }
    };

    stage(0, 0);
    asm volatile("s_waitcnt vmcnt(0)" ::: "memory");
    __builtin_amdgcn_s_barrier();
    __builtin_amdgcn_sched_barrier(0);

    int cur = 0;
    for (int t = 0; t < NT; ++t) {
        if (t + 1 < NT) stage(cur ^ 1, (t + 1) << 6);   // prefetch next tile (other buffer)

        const ushort_t* Ab = Al + cur * 8192;
        const ushort_t* Bb = Bl + cur * 8192;
        #pragma unroll
        for (int c = 0; c < 2; ++c) {
            short8 af[4], bf[4];
            #pragma unroll
            for (int t2 = 0; t2 < 4; ++t2)
                af[t2] = *(const short8*)(Ab + c * 4096 + (wr * 64 + t2 * 16 + lm) * 32 + swq * 8);
            #pragma unroll
            for (int t2 = 0; t2 < 4; ++t2)
                bf[t2] = *(const short8*)(Bb + c * 4096 + (wc * 64 + t2 * 16 + lm) * 32 + swq * 8);
            #pragma unroll
            for (int mt = 0; mt < 4; ++mt)
                #pragma unroll
                for (int nt = 0; nt < 4; ++nt)
                    acc[mt][nt] = __builtin_amdgcn_mfma_f32_16x16x32_bf16(
                        af[mt], bf[nt], acc[mt][nt], 0, 0, 0);
        }

        asm volatile("s_waitcnt vmcnt(0)" ::: "memory");  // next-tile loads done (overlapped)
        __builtin_amdgcn_s_barrier();                     // all waves done reading cur
        __builtin_amdgcn_sched_barrier(0);
        cur ^= 1;
    }

    #pragma unroll
    for (int mt = 0; mt < 4; ++mt)
        #pragma unroll
        for (int nt = 0; nt < 4; ++nt)
            #pragma unroll
            for (int r = 0; r < 4; ++r) {
                int row = m0 + wr * 64 + mt * 16 + quad * 4 + r;
                int col = n0 + wc * 64 + nt * 16 + lm;
                storeC(&C[(size_t)row * N + col], acc[mt][nt][r]);
            }
}

template <typename CT>
__global__ __launch_bounds__(256) void mfma_gemm_bt(
    const ushort_t* __restrict__ A, const ushort_t* __restrict__ Bt,
    CT* __restrict__ C, int N, int K)
{
    __shared__ ushort_t Al[2 * 8192];
    __shared__ ushort_t Bl[2 * 8192];
    gemm_body_128<CT>(A, Bt, C, N, K, blockIdx.y * 128, blockIdx.x * 128, Al, Bl);
}

__global__ __launch_bounds__(256) void mfma_gemm_dual(
    const ushort_t* __restrict__ A1, const ushort_t* __restrict__ Bt1,
    ushort_t* __restrict__ C1, int N1, int K1, int nb1,
    const ushort_t* __restrict__ A2, const ushort_t* __restrict__ Bt2,
    ushort_t* __restrict__ C2, int N2, int K2)
{
    __shared__ ushort_t Al[2 * 8192];
    __shared__ ushort_t Bl[2 * 8192];
    int g = blockIdx.x;
    if (g < nb1) {
        int nbx = N1 / 128;
        gemm_body_128<ushort_t>(A1, Bt1, C1, N1, K1, (g / nbx) * 128, (g % nbx) * 128, Al, Bl);
    } else {
        g -= nb1;
        int nbx = N2 / 128;
        gemm_body_128<ushort_t>(A2, Bt2, C2, N2, K2, (g / nbx) * 128, (g % nbx) * 128, Al, Bl);
    }
}

// online-softmax update for one 16x64 score tile in C layout (DPP); P -> ps[16][72]
__device__ __forceinline__ void softmax_step(
    f32x4 s[4], int k0, int qw, int lm, int quad,
    float m_[4], float l_[4], f32x4 O[8], ushort_t* ps)
{
    const float scale = 0.07216878364870322f;  // 192^-0.5
    #pragma unroll
    for (int r = 0; r < 4; ++r) {
        int qrow = qw + quad * 4 + r;
        float a[4];
        #pragma unroll
        for (int st = 0; st < 4; ++st)
            a[st] = (k0 + st * 16 + lm <= qrow) ? s[st][r] * scale : -1e30f;
        float mx = dpp_max16(fmaxf(fmaxf(a[0], a[1]), fmaxf(a[2], a[3])));
        float mn = fmaxf(m_[r], mx);
        float p[4];
        #pragma unroll
        for (int st = 0; st < 4; ++st) p[st] = __expf(a[st] - mn);
        float alpha = __expf(m_[r] - mn);
        float psum = dpp_sum16((p[0] + p[1]) + (p[2] + p[3]));
        l_[r] = l_[r] * alpha + psum;
        m_[r] = mn;
        #pragma unroll
        for (int c = 0; c < 8; ++c) O[c][r] *= alpha;
        #pragma unroll
        for (int st = 0; st < 4; ++st)
            ps[(quad * 4 + r) * 72 + st * 16 + lm] = f2bf(p[st]);
    }
}

// ---- MFMA flash attention: QBLK=64 / 4 waves / KVBLK=64 (R2 confound removed:
// K-tile stays 64). Staging shared by 4 waves -> 10 gload_lds per wave per tile
// (was 20); LDS 49 KB; grid 16x32=512 blocks -> 2 blocks/CU = 8 waves/CU.
// Validated XOR swizzle kept (conflicts ~0); setprio dropped (measured null). ----
__global__ __launch_bounds__(256) void mla_attn_kernel(
    const ushort_t* __restrict__ qb, const ushort_t* __restrict__ kvb,
    const ushort_t* __restrict__ kpe, const ushort_t* __restrict__ v16t,
    ushort_t* __restrict__ aout16)
{
    __shared__ ushort_t Kn[4 * 64 * 32];   // 16 KB
    __shared__ ushort_t Kr[2 * 64 * 32];   //  8 KB
    __shared__ ushort_t Vt[2 * 128 * 32];  // 16 KB
    __shared__ ushort_t Ps[4][16 * 72];    //  9 KB

    const int h = blockIdx.x;
    const int q0 = 64 * (31 - blockIdx.y);  // heavy-first
    const int w = threadIdx.x >> 6;         // 0..3
    const int lane = threadIdx.x & 63;
    const int lm = lane & 15, quad = lane >> 4;
    const int qw = q0 + 16 * w;
    ushort_t* myPs = Ps[w];

    const int skey = lane >> 2;                               // 0..15
    const int ssw  = ((lane & 3) ^ ((lane >> 3) & 3)) * 8;    // swizzled source slot
    const int swq  = quad ^ ((lm >> 1) & 3);                  // swizzled read slot

    // Q fragments (un-roped source) + fused RoPE on chunks 4/5
    short8 qf[6];
    #pragma unroll
    for (int f = 0; f < 6; ++f)
        qf[f] = *(const short8*)(qb + (size_t)(qw + lm) * 3072 + h * 192 + f * 32 + quad * 8);
    {
        float srow = (float)(qw + lm);
        #pragma unroll
        for (int j = 0; j < 8; ++j) {
            int i = quad * 8 + j;
            float inv = powf(10000.0f, -(2.0f * i) / 64.0f);
            float ang = srow * inv;
            float c = cosf(ang), sn = sinf(ang);
            float x1 = bf2f((ushort_t)qf[4][j]);
            float x2 = bf2f((ushort_t)qf[5][j]);
            qf[4][j] = (short)f2bf(x1 * c - x2 * sn);
            qf[5][j] = (short)f2bf(x2 * c + x1 * sn);
        }
    }

    f32x4 O[8];
    #pragma unroll
    for (int c = 0; c < 8; ++c) O[c] = (f32x4){0.f, 0.f, 0.f, 0.f};
    float m_[4] = {-1e30f, -1e30f, -1e30f, -1e30f};
    float l_[4] = {0.f, 0.f, 0.f, 0.f};

    const int kend = q0 + 64;
    for (int k0 = 0; k0 < kend; k0 += 64) {
        __syncthreads();
        {
            // K-nope: wave w stages dim-chunk f = w, i = 0..3 (4 instr)
            #pragma unroll
            for (int i = 0; i < 4; ++i)
                gload_lds16(kvb + (size_t)(k0 + i * 16 + skey) * 4096 + h * 256 + w * 32 + ssw,
                            Kn + w * 2048 + i * 512 + lane * 8);
            // K-rope: wave w stages f2 = w>>1, i = 2*(w&1)+{0,1} (2 instr)
            #pragma unroll
            for (int ii = 0; ii < 2; ++ii) {
                int i = 2 * (w & 1) + ii;
                gload_lds16(kpe + (size_t)(k0 + i * 16 + skey) * 64 + (w >> 1) * 32 + ssw,
                            Kr + (w >> 1) * 2048 + i * 512 + lane * 8);
            }
            // V^T: wave w stages half = w&1, j = 4*(w>>1)+0..3 (4 instr)
            #pragma unroll
            for (int jj = 0; jj < 4; ++jj) {
                int j = 4 * (w >> 1) + jj;
                gload_lds16(v16t + ((size_t)h * 128 + j * 16 + skey) * S_LEN + k0 + (w & 1) * 32 + ssw,
                            Vt + (w & 1) * 4096 + j * 512 + lane * 8);
            }
        }
        __syncthreads();

        f32x4 s[4];
        #pragma unroll
        for (int st = 0; st < 4; ++st) s[st] = (f32x4){0.f, 0.f, 0.f, 0.f};
        #pragma unroll
        for (int f = 0; f < 4; ++f)
            #pragma unroll
            for (int st = 0; st < 4; ++st) {
                short8 kf = *(const short8*)(Kn + f * 2048 + (st * 16 + lm) * 32 + swq * 8);
                s[st] = __builtin_amdgcn_mfma_f32_16x16x32_bf16(qf[f], kf, s[st], 0, 0, 0);
            }
        #pragma unroll
        for (int f2 = 0; f2 < 2; ++f2)
            #pragma unroll
            for (int st = 0; st < 4; ++st) {
                short8 kf = *(const short8*)(Kr + f2 * 2048 + (st * 16 + lm) * 32 + swq * 8);
                s[st] = __builtin_amdgcn_mfma_f32_16x16x32_bf16(qf[4 + f2], kf, s[st], 0, 0, 0);
            }

        softmax_step(s, k0, qw, lm, quad, m_, l_, O, myPs);

        asm volatile("s_waitcnt lgkmcnt(0)" ::: "memory");
        short8 pf0 = *(const short8*)(myPs + lm * 72 + quad * 8);
        short8 pf1 = *(const short8*)(myPs + lm * 72 + 32 + quad * 8);
        #pragma unroll
        for (int c = 0; c < 8; ++c) {
            short8 vf0 = *(const short8*)(Vt + (c * 16 + lm) * 32 + swq * 8);
            short8 vf1 = *(const short8*)(Vt + 4096 + (c * 16 + lm) * 32 + swq * 8);
            O[c] = __builtin_amdgcn_mfma_f32_16x16x32_bf16(pf0, vf0, O[c], 0, 0, 0);
            O[c] = __builtin_amdgcn_mfma_f32_16x16x32_bf16(pf1, vf1, O[c], 0, 0, 0);
        }
    }
    // epilogue
    #pragma unroll
    for (int c = 0; c < 8; ++c)
        #pragma unroll
        for (int r = 0; r < 4; ++r) {
            int qrow = qw + quad * 4 + r;
            aout16[(size_t)qrow * 2048 + h * D_V + c * 16 + lm] = f2bf(O[c][r] / l_[r]);
        }
}

extern "C" void kernel_launch(void* const* d_in, const int* in_sizes, int n_in,
                              void* d_out, int out_size, void* d_ws, size_t ws_size,
                              hipStream_t stream)
{
    (void)in_sizes; (void)n_in; (void)out_size; (void)ws_size;
    const float* hs   = (const float*)d_in[0];
    const float* Wqa  = (const float*)d_in[1];
    const float* qlnw = (const float*)d_in[2];
    const float* Wqb  = (const float*)d_in[3];
    const float* Wkva = (const float*)d_in[4];
    const float* klnw = (const float*)d_in[5];
    const float* Wkvb = (const float*)d_in[6];
    const float* Wo   = (const float*)d_in[7];
    float* out = (float*)d_out;

    ushort_t* p = (ushort_t*)d_ws;
    ushort_t* hs16   = p; p += (size_t)S_LEN * H_DIM;
    ushort_t* WcatT  = p; p += (size_t)2176 * H_DIM;     // [Wqa^T 1536 ; Wkva^T 640] x 2048
    ushort_t* WqbT   = p; p += (size_t)3072 * Q_LORA;
    ushort_t* WkvbT  = p; p += (size_t)4096 * KV_LORA;
    ushort_t* WoT    = p; p += (size_t)H_DIM * H_DIM;
    ushort_t* cat16r = p; p += (size_t)S_LEN * 2176;     // [qa_raw | ckv_raw | kpe_raw | pad]
    ushort_t* qa16   = p; p += (size_t)S_LEN * Q_LORA;
    ushort_t* qbuf16 = p; p += (size_t)S_LEN * 3072;
    ushort_t* ckv16n = p; p += (size_t)S_LEN * KV_LORA;
    ushort_t* kpe16  = p; p += (size_t)S_LEN * D_ROPE;
    ushort_t* kv16   = p; p += (size_t)S_LEN * 4096;
    ushort_t* v16t   = p; p += (size_t)NH * D_V * S_LEN;
    ushort_t* aout16 = p; p += (size_t)S_LEN * 2048;

    // 1. all conversions in one launch (hs + 5 weight transposes)
    unified_conv<<<19200, 256, 0, stream>>>(
        hs, hs16, Wqa, Wkva, Wqb, Wkvb, Wo, WcatT, WqbT, WkvbT, WoT);
    // 2. cat16r = hs16 @ WcatT^T  [2048 x 2176, K=2048]  (fused Wqa + Wkva)
    mfma_gemm_bt<ushort_t><<<dim3(2176 / 128, S_LEN / 128), 256, 0, stream>>>(
        hs16, WcatT, cat16r, 2176, H_DIM);
    // 3. fused rmsnorm-q / rmsnorm-kv / rope-k
    fused_norm_ropek<<<4096 + 256, 256, 0, stream>>>(cat16r, qa16, ckv16n, kpe16, qlnw, klnw);
    // 4. grouped GEMM: qbuf16 = qa16 @ WqbT^T [2048x3072,K=1536] + kv16 = ckv16n @ WkvbT^T [2048x4096,K=512]
    mfma_gemm_dual<<<384 + 512, 256, 0, stream>>>(
        qa16, WqbT, qbuf16, 3072, Q_LORA, 384,
        ckv16n, WkvbT, kv16, 4096, KV_LORA);
    // 5. V transpose
    conv_vT_kernel<<<dim3(S_LEN / 32, D_V / 32, NH), 256, 0, stream>>>(kv16, v16t);
    // 6. attention (QBLK=64, 4 waves, KVBLK=64, swizzled staging)
    mla_attn_kernel<<<dim3(NH, 32), 256, 0, stream>>>(qbuf16, kv16, kpe16, v16t, aout16);
    // 7. out = aout16 @ WoT^T [2048 x 2048, K=2048], fp32 store
    mfma_gemm_bt<float><<<dim3(H_DIM / 128, S_LEN / 128), 256, 0, stream>>>(
        aout16, WoT, out, H_DIM, H_DIM);
}

// Round 5
// 325.772 us; speedup vs baseline: 1.4690x; 1.0454x over previous
//
#include <hip/hip_runtime.h>
#include <hip/hip_bf16.h>
#include <math.h>

#define S_LEN 2048
#define H_DIM 2048
#define NH 16
#define Q_LORA 1536
#define KV_LORA 512
#define D_NOPE 128
#define D_ROPE 64
#define D_V 128
#define D_QK 192

typedef unsigned short ushort_t;
typedef __attribute__((ext_vector_type(8))) short short8;
typedef __attribute__((ext_vector_type(4))) float f32x4;

__device__ __forceinline__ ushort_t f2bf(float f) {
    unsigned int u = __float_as_uint(f);
    u = (u + 0x7FFFu + ((u >> 16) & 1u)) >> 16;
    return (ushort_t)u;
}
__device__ __forceinline__ float bf2f(ushort_t u) {
    return __uint_as_float(((unsigned int)u) << 16);
}

__device__ __forceinline__ void storeC(float* p, float v) { *p = v; }
__device__ __forceinline__ void storeC(ushort_t* p, float v) { *p = f2bf(v); }

__device__ __forceinline__ void gload_lds16(const ushort_t* g, ushort_t* l) {
    __builtin_amdgcn_global_load_lds(
        (const __attribute__((address_space(1))) unsigned int*)(const void*)g,
        (__attribute__((address_space(3))) unsigned int*)(void*)l, 16, 0, 0);
}

// 16-lane DPP-row reductions (pure VALU)
__device__ __forceinline__ float dpp_max16(float x) {
    x = fmaxf(x, __int_as_float(__builtin_amdgcn_update_dpp(0, __float_as_int(x), 0xB1, 0xF, 0xF, true)));
    x = fmaxf(x, __int_as_float(__builtin_amdgcn_update_dpp(0, __float_as_int(x), 0x4E, 0xF, 0xF, true)));
    x = fmaxf(x, __int_as_float(__builtin_amdgcn_update_dpp(0, __float_as_int(x), 0x124, 0xF, 0xF, true)));
    x = fmaxf(x, __int_as_float(__builtin_amdgcn_update_dpp(0, __float_as_int(x), 0x128, 0xF, 0xF, true)));
    return x;
}
__device__ __forceinline__ float dpp_sum16(float x) {
    x += __int_as_float(__builtin_amdgcn_update_dpp(0, __float_as_int(x), 0xB1, 0xF, 0xF, true));
    x += __int_as_float(__builtin_amdgcn_update_dpp(0, __float_as_int(x), 0x4E, 0xF, 0xF, true));
    x += __int_as_float(__builtin_amdgcn_update_dpp(0, __float_as_int(x), 0x124, 0xF, 0xF, true));
    x += __int_as_float(__builtin_amdgcn_update_dpp(0, __float_as_int(x), 0x128, 0xF, 0xF, true));
    return x;
}

// -------- unified conversion: hs f32->bf16 + 5 weight transposes, one launch --------
__device__ __forceinline__ void convT_body(
    const float* __restrict__ W, ushort_t* __restrict__ Wt,
    int K, int N, int n0, int k0, float (*tile)[33])
{
    const int tr = threadIdx.x >> 5, tc = threadIdx.x & 31;
    #pragma unroll
    for (int i = 0; i < 4; ++i) {
        int r = tr + i * 8;
        float v = 0.f;
        if (n0 + tc < N) v = W[(size_t)(k0 + r) * N + n0 + tc];
        tile[r][tc] = v;
    }
    __syncthreads();
    #pragma unroll
    for (int i = 0; i < 4; ++i) {
        int r = tr + i * 8;
        Wt[(size_t)(n0 + r) * K + k0 + tc] = f2bf(tile[tc][r]);
    }
}

__global__ __launch_bounds__(256) void unified_conv(
    const float* __restrict__ hs, ushort_t* __restrict__ hs16,
    const float* __restrict__ Wqa, const float* __restrict__ Wkva,
    const float* __restrict__ Wqb, const float* __restrict__ Wkvb,
    const float* __restrict__ Wo,
    ushort_t* __restrict__ WcatT, ushort_t* __restrict__ WqbT,
    ushort_t* __restrict__ WkvbT, ushort_t* __restrict__ WoT)
{
    __shared__ float tile[32][33];
    int b = blockIdx.x;
    if (b < 4096) {   // hs elementwise
        int base = (b * 256 + threadIdx.x) * 4;
        float4 v = *(const float4*)(hs + base);
        hs16[base + 0] = f2bf(v.x);
        hs16[base + 1] = f2bf(v.y);
        hs16[base + 2] = f2bf(v.z);
        hs16[base + 3] = f2bf(v.w);
        return;
    }
    b -= 4096;
    const float* W; ushort_t* Wt; int K, N, nbx;
    if (b < 3072)        {            W = Wqa;  Wt = WcatT;                              K = 2048; N = 1536; nbx = 48;  }
    else if (b < 4352)   { b -= 3072; W = Wkva; Wt = WcatT + (size_t)Q_LORA * H_DIM;     K = 2048; N = 576;  nbx = 20;  }
    else if (b < 8960)   { b -= 4352; W = Wqb;  Wt = WqbT;                               K = 1536; N = 3072; nbx = 96;  }
    else if (b < 11008)  { b -= 8960; W = Wkvb; Wt = WkvbT;                              K = 512;  N = 4096; nbx = 128; }
    else                 { b -= 11008; W = Wo;  Wt = WoT;                                K = 2048; N = 2048; nbx = 64;  }
    convT_body(W, Wt, K, N, (b % nbx) * 32, (b / nbx) * 32, tile);
}

// ------- fused: rmsnorm-q (blocks 0..2047) + rmsnorm-kv (2048..4095) + rope-k (4096..) -------
__global__ __launch_bounds__(256) void fused_norm_ropek(
    const ushort_t* __restrict__ cat16r, ushort_t* __restrict__ qa16,
    ushort_t* __restrict__ ckv16n, ushort_t* __restrict__ kpe16,
    const float* __restrict__ qlnw, const float* __restrict__ klnw)
{
    __shared__ float red[4];
    const int b = blockIdx.x;
    if (b < 4096) {
        const bool isQ = (b < 2048);
        const int row = isQ ? b : b - 2048;
        const int K = isQ ? Q_LORA : KV_LORA;
        const ushort_t* x = cat16r + (size_t)row * 2176 + (isQ ? 0 : Q_LORA);
        ushort_t* y = (isQ ? qa16 + (size_t)row * Q_LORA : ckv16n + (size_t)row * KV_LORA);
        const float* wv = isQ ? qlnw : klnw;
        float ss = 0.f;
        for (int i = threadIdx.x; i < K; i += 256) { float v = bf2f(x[i]); ss += v * v; }
        #pragma unroll
        for (int off = 32; off > 0; off >>= 1) ss += __shfl_down(ss, off);
        int lane = threadIdx.x & 63, wid = threadIdx.x >> 6;
        if (lane == 0) red[wid] = ss;
        __syncthreads();
        float tot = red[0] + red[1] + red[2] + red[3];
        float rs = rsqrtf(tot / (float)K + 1e-6f);
        for (int i = threadIdx.x; i < K; i += 256)
            y[i] = f2bf(bf2f(x[i]) * rs * wv[i]);
    } else {
        int idx = (b - 4096) * 256 + threadIdx.x;
        if (idx >= S_LEN * 32) return;
        int i = idx & 31;
        int s = idx >> 5;
        float inv = powf(10000.0f, -(2.0f * i) / 64.0f);
        float ang = (float)s * inv;
        float c = cosf(ang), sn = sinf(ang);
        const ushort_t* p = cat16r + (size_t)s * 2176 + Q_LORA + KV_LORA;
        ushort_t* q = kpe16 + (size_t)s * D_ROPE;
        float x1 = bf2f(p[i]), x2 = bf2f(p[i + 32]);
        q[i]      = f2bf(x1 * c - x2 * sn);
        q[i + 32] = f2bf(x2 * c + x1 * sn);
    }
}

// ---------------- V transpose: kv16[s][h*256+128+dv] -> v16t[h][dv][s] ----------------
__global__ __launch_bounds__(256) void conv_vT_kernel(
    const ushort_t* __restrict__ kv, ushort_t* __restrict__ v16t)
{
    __shared__ ushort_t tile[32][33];
    const int h = blockIdx.z;
    const int s0 = blockIdx.x * 32, d0 = blockIdx.y * 32;
    const int tr = threadIdx.x >> 5, tc = threadIdx.x & 31;
    #pragma unroll
    for (int i = 0; i < 4; ++i) {
        int r = tr + i * 8;  // s
        tile[r][tc] = kv[(size_t)(s0 + r) * 4096 + h * 256 + D_NOPE + d0 + tc];
    }
    __syncthreads();
    #pragma unroll
    for (int i = 0; i < 4; ++i) {
        int r = tr + i * 8;  // dv
        v16t[(size_t)h * D_V * S_LEN + (size_t)(d0 + r) * S_LEN + s0 + tc] = tile[tc][r];
    }
}

// ---- MFMA GEMM body, 128x128 tile, 4 waves 2x2, acc[4][4], BK=64.
// 2-DEEP pipeline (T4 counted-vmcnt): tiles t and t+1 staged ahead; iteration
// waits vmcnt(8) (tile t landed, t+1 in flight), computes, barriers, stages
// t+2 into the released buffer. Cover per load = ~2 compute phases >= L2
// latency. Round-4's 1-deep vmcnt(0) gave only ~1 compute phase of cover.
// XOR bank-swizzle kept (R2-validated). ----
template <typename CT>
__device__ __forceinline__ void gemm_body_128(
    const ushort_t* __restrict__ A, const ushort_t* __restrict__ Bt,
    CT* __restrict__ C, int N, int K, int m0, int n0,
    ushort_t* Al, ushort_t* Bl)  // each 2 bufs * 8192 ushorts = 32 KB
{
    const int tid = threadIdx.x;
    const int lane = tid & 63;
    const int w = tid >> 6;
    const int lm = lane & 15, quad = lane >> 4;
    const int wr = w >> 1, wc = w & 1;

    f32x4 acc[4][4];
    #pragma unroll
    for (int a = 0; a < 4; ++a)
        #pragma unroll
        for (int b = 0; b < 4; ++b) acc[a][b] = (f32x4){0.f, 0.f, 0.f, 0.f};

    const int rrow = tid >> 2;                                // 0..63
    const int rcsw = ((tid & 3) ^ ((tid >> 3) & 3)) * 8;      // swizzled source k-slot
    const int swq  = quad ^ ((lm >> 1) & 3);                  // swizzled read slot

    const int NT = K >> 6;

    auto stage = [&](int buf, int k0) {
        #pragma unroll
        for (int c = 0; c < 2; ++c)
            #pragma unroll
            for (int half = 0; half < 2; ++half) {
                gload_lds16(A + (size_t)(m0 + half * 64 + rrow) * K + k0 + c * 32 + rcsw,
                            Al + buf * 8192 + c * 4096 + half * 2048 + tid * 8);
                gload_lds16(Bt + (size_t)(n0 + half * 64 + rrow) * K + k0 + c * 32 + rcsw,
                            Bl + buf * 8192 + c * 4096 + half * 2048 + tid * 8);
            }
    };

    stage(0, 0);       // 8 loads/wave
    stage(1, 64);      // +8 (NT >= 8 for all our shapes)

    int cur = 0;
    for (int t = 0; t < NT; ++t) {
        if (t + 1 < NT) asm volatile("s_waitcnt vmcnt(8)" ::: "memory");
        else            asm volatile("s_waitcnt vmcnt(0)" ::: "memory");
        __builtin_amdgcn_s_barrier();
        __builtin_amdgcn_sched_barrier(0);

        const ushort_t* Ab = Al + cur * 8192;
        const ushort_t* Bb = Bl + cur * 8192;
        #pragma unroll
        for (int c = 0; c < 2; ++c) {
            short8 af[4], bf[4];
            #pragma unroll
            for (int t2 = 0; t2 < 4; ++t2)
                af[t2] = *(const short8*)(Ab + c * 4096 + (wr * 64 + t2 * 16 + lm) * 32 + swq * 8);
            #pragma unroll
            for (int t2 = 0; t2 < 4; ++t2)
                bf[t2] = *(const short8*)(Bb + c * 4096 + (wc * 64 + t2 * 16 + lm) * 32 + swq * 8);
            #pragma unroll
            for (int mt = 0; mt < 4; ++mt)
                #pragma unroll
                for (int nt = 0; nt < 4; ++nt)
                    acc[mt][nt] = __builtin_amdgcn_mfma_f32_16x16x32_bf16(
                        af[mt], bf[nt], acc[mt][nt], 0, 0, 0);
        }

        __builtin_amdgcn_s_barrier();       // all waves done reading buf cur
        __builtin_amdgcn_sched_barrier(0);
        if (t + 2 < NT) stage(cur, (t + 2) << 6);   // overwrite released buffer
        cur ^= 1;
    }

    #pragma unroll
    for (int mt = 0; mt < 4; ++mt)
        #pragma unroll
        for (int nt = 0; nt < 4; ++nt)
            #pragma unroll
            for (int r = 0; r < 4; ++r) {
                int row = m0 + wr * 64 + mt * 16 + quad * 4 + r;
                int col = n0 + wc * 64 + nt * 16 + lm;
                storeC(&C[(size_t)row * N + col], acc[mt][nt][r]);
            }
}

template <typename CT>
__global__ __launch_bounds__(256) void mfma_gemm_bt(
    const ushort_t* __restrict__ A, const ushort_t* __restrict__ Bt,
    CT* __restrict__ C, int N, int K)
{
    __shared__ ushort_t Al[2 * 8192];
    __shared__ ushort_t Bl[2 * 8192];
    gemm_body_128<CT>(A, Bt, C, N, K, blockIdx.y * 128, blockIdx.x * 128, Al, Bl);
}

__global__ __launch_bounds__(256) void mfma_gemm_dual(
    const ushort_t* __restrict__ A1, const ushort_t* __restrict__ Bt1,
    ushort_t* __restrict__ C1, int N1, int K1, int nb1,
    const ushort_t* __restrict__ A2, const ushort_t* __restrict__ Bt2,
    ushort_t* __restrict__ C2, int N2, int K2)
{
    __shared__ ushort_t Al[2 * 8192];
    __shared__ ushort_t Bl[2 * 8192];
    int g = blockIdx.x;
    if (g < nb1) {
        int nbx = N1 / 128;
        gemm_body_128<ushort_t>(A1, Bt1, C1, N1, K1, (g / nbx) * 128, (g % nbx) * 128, Al, Bl);
    } else {
        g -= nb1;
        int nbx = N2 / 128;
        gemm_body_128<ushort_t>(A2, Bt2, C2, N2, K2, (g / nbx) * 128, (g % nbx) * 128, Al, Bl);
    }
}

// online-softmax update for one 16x64 score tile in C layout (DPP); P -> ps[16][72]
__device__ __forceinline__ void softmax_step(
    f32x4 s[4], int k0, int qw, int lm, int quad,
    float m_[4], float l_[4], f32x4 O[8], ushort_t* ps)
{
    const float scale = 0.07216878364870322f;  // 192^-0.5
    #pragma unroll
    for (int r = 0; r < 4; ++r) {
        int qrow = qw + quad * 4 + r;
        float a[4];
        #pragma unroll
        for (int st = 0; st < 4; ++st)
            a[st] = (k0 + st * 16 + lm <= qrow) ? s[st][r] * scale : -1e30f;
        float mx = dpp_max16(fmaxf(fmaxf(a[0], a[1]), fmaxf(a[2], a[3])));
        float mn = fmaxf(m_[r], mx);
        float p[4];
        #pragma unroll
        for (int st = 0; st < 4; ++st) p[st] = __expf(a[st] - mn);
        float alpha = __expf(m_[r] - mn);
        float psum = dpp_sum16((p[0] + p[1]) + (p[2] + p[3]));
        l_[r] = l_[r] * alpha + psum;
        m_[r] = mn;
        #pragma unroll
        for (int c = 0; c < 8; ++c) O[c][r] *= alpha;
        #pragma unroll
        for (int st = 0; st < 4; ++st)
            ps[(quad * 4 + r) * 72 + st * 16 + lm] = f2bf(p[st]);
    }
}

// ---- MFMA flash attention: QBLK=64 / 4 waves / KVBLK=64, SPLIT-STAGING
// pipeline with counted vmcnt (steady state never drains to 0):
//   K double-buffered, prefetched 1 tile ahead (cover = full prev tile);
//   V single-buffered, issued at tile start, waited vmcnt(6) only after
//   QK+softmax (T14: HBM/L2 latency hides under compute).
// Per-wave queue at QK-wait: [K(t)x6 | V(t)x4 K(t+1)x6] -> vmcnt(10);
// at PV-wait: [V(t)x4 | K(t+1)x6] -> vmcnt(6). Last tile: 4 / 0.
// LDS 73 KB -> 2 blocks/CU. XOR swizzle kept (conflicts ~0). ----
__global__ __launch_bounds__(256) void mla_attn_kernel(
    const ushort_t* __restrict__ qb, const ushort_t* __restrict__ kvb,
    const ushort_t* __restrict__ kpe, const ushort_t* __restrict__ v16t,
    ushort_t* __restrict__ aout16)
{
    __shared__ ushort_t Kn[2 * 4 * 64 * 32];   // 32 KB (2 bufs)
    __shared__ ushort_t Kr[2 * 2 * 64 * 32];   // 16 KB (2 bufs)
    __shared__ ushort_t Vt[2 * 128 * 32];      // 16 KB (single buf)
    __shared__ ushort_t Ps[4][16 * 72];        //  9 KB

    const int h = blockIdx.x;
    const int q0 = 64 * (31 - blockIdx.y);  // heavy-first
    const int w = threadIdx.x >> 6;         // 0..3
    const int lane = threadIdx.x & 63;
    const int lm = lane & 15, quad = lane >> 4;
    const int qw = q0 + 16 * w;
    ushort_t* myPs = Ps[w];

    const int skey = lane >> 2;                               // 0..15
    const int ssw  = ((lane & 3) ^ ((lane >> 3) & 3)) * 8;    // swizzled source slot
    const int swq  = quad ^ ((lm >> 1) & 3);                  // swizzled read slot

    // Q fragments (un-roped source) + fused RoPE on chunks 4/5
    short8 qf[6];
    #pragma unroll
    for (int f = 0; f < 6; ++f)
        qf[f] = *(const short8*)(qb + (size_t)(qw + lm) * 3072 + h * 192 + f * 32 + quad * 8);
    {
        float srow = (float)(qw + lm);
        #pragma unroll
        for (int j = 0; j < 8; ++j) {
            int i = quad * 8 + j;
            float inv = powf(10000.0f, -(2.0f * i) / 64.0f);
            float ang = srow * inv;
            float c = cosf(ang), sn = sinf(ang);
            float x1 = bf2f((ushort_t)qf[4][j]);
            float x2 = bf2f((ushort_t)qf[5][j]);
            qf[4][j] = (short)f2bf(x1 * c - x2 * sn);
            qf[5][j] = (short)f2bf(x2 * c + x1 * sn);
        }
    }
    // drain Q loads so vmcnt bookkeeping below is exact
    asm volatile("s_waitcnt vmcnt(0)" ::: "memory");

    f32x4 O[8];
    #pragma unroll
    for (int c = 0; c < 8; ++c) O[c] = (f32x4){0.f, 0.f, 0.f, 0.f};
    float m_[4] = {-1e30f, -1e30f, -1e30f, -1e30f};
    float l_[4] = {0.f, 0.f, 0.f, 0.f};

    // per-wave staging: Kn 4 loads, Kr 2 loads, V 4 loads
    auto stageK = [&](int buf, int k0s) {
        #pragma unroll
        for (int i = 0; i < 4; ++i)
            gload_lds16(kvb + (size_t)(k0s + i * 16 + skey) * 4096 + h * 256 + w * 32 + ssw,
                        Kn + buf * 8192 + w * 2048 + i * 512 + lane * 8);
        #pragma unroll
        for (int ii = 0; ii < 2; ++ii) {
            int i = 2 * (w & 1) + ii;
            gload_lds16(kpe + (size_t)(k0s + i * 16 + skey) * 64 + (w >> 1) * 32 + ssw,
                        Kr + buf * 4096 + (w >> 1) * 2048 + i * 512 + lane * 8);
        }
    };
    auto stageV = [&](int k0s) {
        #pragma unroll
        for (int jj = 0; jj < 4; ++jj) {
            int j = 4 * (w >> 1) + jj;
            gload_lds16(v16t + ((size_t)h * 128 + j * 16 + skey) * S_LEN + k0s + (w & 1) * 32 + ssw,
                        Vt + (w & 1) * 4096 + j * 512 + lane * 8);
        }
    };

    const int nt = q0 / 64 + 1;
    stageK(0, 0);   // 6 outstanding/wave

    for (int t = 0; t < nt; ++t) {
        const int k0 = t * 64;
        const bool hasNext = (t + 1 < nt);
        const int kb = t & 1;

        stageV(k0);                                // +4
        if (hasNext) stageK(kb ^ 1, k0 + 64);      // +6

        if (hasNext) asm volatile("s_waitcnt vmcnt(10)" ::: "memory");  // K(t) landed
        else         asm volatile("s_waitcnt vmcnt(4)"  ::: "memory");
        __builtin_amdgcn_s_barrier();
        __builtin_amdgcn_sched_barrier(0);

        // ---- QK^T from Kn/Kr buf kb ----
        f32x4 s[4];
        #pragma unroll
        for (int st = 0; st < 4; ++st) s[st] = (f32x4){0.f, 0.f, 0.f, 0.f};
        #pragma unroll
        for (int f = 0; f < 4; ++f)
            #pragma unroll
            for (int st = 0; st < 4; ++st) {
                short8 kf = *(const short8*)(Kn + kb * 8192 + f * 2048 + (st * 16 + lm) * 32 + swq * 8);
                s[st] = __builtin_amdgcn_mfma_f32_16x16x32_bf16(qf[f], kf, s[st], 0, 0, 0);
            }
        #pragma unroll
        for (int f2 = 0; f2 < 2; ++f2)
            #pragma unroll
            for (int st = 0; st < 4; ++st) {
                short8 kf = *(const short8*)(Kr + kb * 4096 + f2 * 2048 + (st * 16 + lm) * 32 + swq * 8);
                s[st] = __builtin_amdgcn_mfma_f32_16x16x32_bf16(qf[4 + f2], kf, s[st], 0, 0, 0);
            }

        softmax_step(s, k0, qw, lm, quad, m_, l_, O, myPs);

        // V(t) landed (K(t+1) still in flight) + own Ps writes visible
        if (hasNext) asm volatile("s_waitcnt vmcnt(6) lgkmcnt(0)" ::: "memory");
        else         asm volatile("s_waitcnt vmcnt(0) lgkmcnt(0)" ::: "memory");
        __builtin_amdgcn_s_barrier();
        __builtin_amdgcn_sched_barrier(0);

        short8 pf0 = *(const short8*)(myPs + lm * 72 + quad * 8);
        short8 pf1 = *(const short8*)(myPs + lm * 72 + 32 + quad * 8);
        #pragma unroll
        for (int c = 0; c < 8; ++c) {
            short8 vf0 = *(const short8*)(Vt + (c * 16 + lm) * 32 + swq * 8);
            short8 vf1 = *(const short8*)(Vt + 4096 + (c * 16 + lm) * 32 + swq * 8);
            O[c] = __builtin_amdgcn_mfma_f32_16x16x32_bf16(pf0, vf0, O[c], 0, 0, 0);
            O[c] = __builtin_amdgcn_mfma_f32_16x16x32_bf16(pf1, vf1, O[c], 0, 0, 0);
        }

        __builtin_amdgcn_s_barrier();   // release Vt and Kn/Kr[kb] for next iter's staging
        __builtin_amdgcn_sched_barrier(0);
    }

    // epilogue
    #pragma unroll
    for (int c = 0; c < 8; ++c)
        #pragma unroll
        for (int r = 0; r < 4; ++r) {
            int qrow = qw + quad * 4 + r;
            aout16[(size_t)qrow * 2048 + h * D_V + c * 16 + lm] = f2bf(O[c][r] / l_[r]);
        }
}

extern "C" void kernel_launch(void* const* d_in, const int* in_sizes, int n_in,
                              void* d_out, int out_size, void* d_ws, size_t ws_size,
                              hipStream_t stream)
{
    (void)in_sizes; (void)n_in; (void)out_size; (void)ws_size;
    const float* hs   = (const float*)d_in[0];
    const float* Wqa  = (const float*)d_in[1];
    const float* qlnw = (const float*)d_in[2];
    const float* Wqb  = (const float*)d_in[3];
    const float* Wkva = (const float*)d_in[4];
    const float* klnw = (const float*)d_in[5];
    const float* Wkvb = (const float*)d_in[6];
    const float* Wo   = (const float*)d_in[7];
    float* out = (float*)d_out;

    ushort_t* p = (ushort_t*)d_ws;
    ushort_t* hs16   = p; p += (size_t)S_LEN * H_DIM;
    ushort_t* WcatT  = p; p += (size_t)2176 * H_DIM;     // [Wqa^T 1536 ; Wkva^T 640] x 2048
    ushort_t* WqbT   = p; p += (size_t)3072 * Q_LORA;
    ushort_t* WkvbT  = p; p += (size_t)4096 * KV_LORA;
    ushort_t* WoT    = p; p += (size_t)H_DIM * H_DIM;
    ushort_t* cat16r = p; p += (size_t)S_LEN * 2176;     // [qa_raw | ckv_raw | kpe_raw | pad]
    ushort_t* qa16   = p; p += (size_t)S_LEN * Q_LORA;
    ushort_t* qbuf16 = p; p += (size_t)S_LEN * 3072;
    ushort_t* ckv16n = p; p += (size_t)S_LEN * KV_LORA;
    ushort_t* kpe16  = p; p += (size_t)S_LEN * D_ROPE;
    ushort_t* kv16   = p; p += (size_t)S_LEN * 4096;
    ushort_t* v16t   = p; p += (size_t)NH * D_V * S_LEN;
    ushort_t* aout16 = p; p += (size_t)S_LEN * 2048;

    // 1. all conversions in one launch (hs + 5 weight transposes)
    unified_conv<<<19200, 256, 0, stream>>>(
        hs, hs16, Wqa, Wkva, Wqb, Wkvb, Wo, WcatT, WqbT, WkvbT, WoT);
    // 2. cat16r = hs16 @ WcatT^T  [2048 x 2176, K=2048]  (fused Wqa + Wkva)
    mfma_gemm_bt<ushort_t><<<dim3(2176 / 128, S_LEN / 128), 256, 0, stream>>>(
        hs16, WcatT, cat16r, 2176, H_DIM);
    // 3. fused rmsnorm-q / rmsnorm-kv / rope-k
    fused_norm_ropek<<<4096 + 256, 256, 0, stream>>>(cat16r, qa16, ckv16n, kpe16, qlnw, klnw);
    // 4. grouped GEMM: qbuf16 = qa16 @ WqbT^T [2048x3072,K=1536] + kv16 = ckv16n @ WkvbT^T [2048x4096,K=512]
    mfma_gemm_dual<<<384 + 512, 256, 0, stream>>>(
        qa16, WqbT, qbuf16, 3072, Q_LORA, 384,
        ckv16n, WkvbT, kv16, 4096, KV_LORA);
    // 5. V transpose
    conv_vT_kernel<<<dim3(S_LEN / 32, D_V / 32, NH), 256, 0, stream>>>(kv16, v16t);
    // 6. attention (QBLK=64, 4 waves, KVBLK=64, split-staging counted-vmcnt pipeline)
    mla_attn_kernel<<<dim3(NH, 32), 256, 0, stream>>>(qbuf16, kv16, kpe16, v16t, aout16);
    // 7. out = aout16 @ WoT^T [2048 x 2048, K=2048], fp32 store
    mfma_gemm_bt<float><<<dim3(H_DIM / 128, S_LEN / 128), 256, 0, stream>>>(
        aout16, WoT, out, H_DIM, H_DIM);
}

// Round 6
// 324.590 us; speedup vs baseline: 1.4743x; 1.0036x over previous
//
#include <hip/hip_runtime.h>
#include <hip/hip_bf16.h>
#include <math.h>

#define S_LEN 2048
#define H_DIM 2048
#define NH 16
#define Q_LORA 1536
#define KV_LORA 512
#define D_NOPE 128
#define D_ROPE 64
#define D_V 128
#define D_QK 192

typedef unsigned short ushort_t;
typedef __attribute__((ext_vector_type(8))) short short8;
typedef __attribute__((ext_vector_type(4))) float f32x4;

__device__ __forceinline__ ushort_t f2bf(float f) {
    unsigned int u = __float_as_uint(f);
    u = (u + 0x7FFFu + ((u >> 16) & 1u)) >> 16;
    return (ushort_t)u;
}
__device__ __forceinline__ float bf2f(ushort_t u) {
    return __uint_as_float(((unsigned int)u) << 16);
}

__device__ __forceinline__ void storeC(float* p, float v) { *p = v; }
__device__ __forceinline__ void storeC(ushort_t* p, float v) { *p = f2bf(v); }

__device__ __forceinline__ void gload_lds16(const ushort_t* g, ushort_t* l) {
    __builtin_amdgcn_global_load_lds(
        (const __attribute__((address_space(1))) unsigned int*)(const void*)g,
        (__attribute__((address_space(3))) unsigned int*)(void*)l, 16, 0, 0);
}

// 16-lane DPP-row reductions (pure VALU)
__device__ __forceinline__ float dpp_max16(float x) {
    x = fmaxf(x, __int_as_float(__builtin_amdgcn_update_dpp(0, __float_as_int(x), 0xB1, 0xF, 0xF, true)));
    x = fmaxf(x, __int_as_float(__builtin_amdgcn_update_dpp(0, __float_as_int(x), 0x4E, 0xF, 0xF, true)));
    x = fmaxf(x, __int_as_float(__builtin_amdgcn_update_dpp(0, __float_as_int(x), 0x124, 0xF, 0xF, true)));
    x = fmaxf(x, __int_as_float(__builtin_amdgcn_update_dpp(0, __float_as_int(x), 0x128, 0xF, 0xF, true)));
    return x;
}
__device__ __forceinline__ float dpp_sum16(float x) {
    x += __int_as_float(__builtin_amdgcn_update_dpp(0, __float_as_int(x), 0xB1, 0xF, 0xF, true));
    x += __int_as_float(__builtin_amdgcn_update_dpp(0, __float_as_int(x), 0x4E, 0xF, 0xF, true));
    x += __int_as_float(__builtin_amdgcn_update_dpp(0, __float_as_int(x), 0x124, 0xF, 0xF, true));
    x += __int_as_float(__builtin_amdgcn_update_dpp(0, __float_as_int(x), 0x128, 0xF, 0xF, true));
    return x;
}

// -------- unified conversion: hs f32->bf16 + 5 weight transposes, one launch --------
__device__ __forceinline__ void convT_body(
    const float* __restrict__ W, ushort_t* __restrict__ Wt,
    int K, int N, int n0, int k0, float (*tile)[33])
{
    const int tr = threadIdx.x >> 5, tc = threadIdx.x & 31;
    #pragma unroll
    for (int i = 0; i < 4; ++i) {
        int r = tr + i * 8;
        float v = 0.f;
        if (n0 + tc < N) v = W[(size_t)(k0 + r) * N + n0 + tc];
        tile[r][tc] = v;
    }
    __syncthreads();
    #pragma unroll
    for (int i = 0; i < 4; ++i) {
        int r = tr + i * 8;
        Wt[(size_t)(n0 + r) * K + k0 + tc] = f2bf(tile[tc][r]);
    }
}

__global__ __launch_bounds__(256) void unified_conv(
    const float* __restrict__ hs, ushort_t* __restrict__ hs16,
    const float* __restrict__ Wqa, const float* __restrict__ Wkva,
    const float* __restrict__ Wqb, const float* __restrict__ Wkvb,
    const float* __restrict__ Wo,
    ushort_t* __restrict__ WcatT, ushort_t* __restrict__ WqbT,
    ushort_t* __restrict__ WkvbT, ushort_t* __restrict__ WoT)
{
    __shared__ float tile[32][33];
    int b = blockIdx.x;
    if (b < 4096) {   // hs elementwise
        int base = (b * 256 + threadIdx.x) * 4;
        float4 v = *(const float4*)(hs + base);
        hs16[base + 0] = f2bf(v.x);
        hs16[base + 1] = f2bf(v.y);
        hs16[base + 2] = f2bf(v.z);
        hs16[base + 3] = f2bf(v.w);
        return;
    }
    b -= 4096;
    const float* W; ushort_t* Wt; int K, N, nbx;
    if (b < 3072)        {            W = Wqa;  Wt = WcatT;                              K = 2048; N = 1536; nbx = 48;  }
    else if (b < 4352)   { b -= 3072; W = Wkva; Wt = WcatT + (size_t)Q_LORA * H_DIM;     K = 2048; N = 576;  nbx = 20;  }
    else if (b < 8960)   { b -= 4352; W = Wqb;  Wt = WqbT;                               K = 1536; N = 3072; nbx = 96;  }
    else if (b < 11008)  { b -= 8960; W = Wkvb; Wt = WkvbT;                              K = 512;  N = 4096; nbx = 128; }
    else                 { b -= 11008; W = Wo;  Wt = WoT;                                K = 2048; N = 2048; nbx = 64;  }
    convT_body(W, Wt, K, N, (b % nbx) * 32, (b / nbx) * 32, tile);
}

// ------- fused: rmsnorm-q (blocks 0..2047) + rmsnorm-kv (2048..4095) + rope-k (4096..) -------
__global__ __launch_bounds__(256) void fused_norm_ropek(
    const ushort_t* __restrict__ cat16r, ushort_t* __restrict__ qa16,
    ushort_t* __restrict__ ckv16n, ushort_t* __restrict__ kpe16,
    const float* __restrict__ qlnw, const float* __restrict__ klnw)
{
    __shared__ float red[4];
    const int b = blockIdx.x;
    if (b < 4096) {
        const bool isQ = (b < 2048);
        const int row = isQ ? b : b - 2048;
        const int K = isQ ? Q_LORA : KV_LORA;
        const ushort_t* x = cat16r + (size_t)row * 2176 + (isQ ? 0 : Q_LORA);
        ushort_t* y = (isQ ? qa16 + (size_t)row * Q_LORA : ckv16n + (size_t)row * KV_LORA);
        const float* wv = isQ ? qlnw : klnw;
        float ss = 0.f;
        for (int i = threadIdx.x; i < K; i += 256) { float v = bf2f(x[i]); ss += v * v; }
        #pragma unroll
        for (int off = 32; off > 0; off >>= 1) ss += __shfl_down(ss, off);
        int lane = threadIdx.x & 63, wid = threadIdx.x >> 6;
        if (lane == 0) red[wid] = ss;
        __syncthreads();
        float tot = red[0] + red[1] + red[2] + red[3];
        float rs = rsqrtf(tot / (float)K + 1e-6f);
        for (int i = threadIdx.x; i < K; i += 256)
            y[i] = f2bf(bf2f(x[i]) * rs * wv[i]);
    } else {
        int idx = (b - 4096) * 256 + threadIdx.x;
        if (idx >= S_LEN * 32) return;
        int i = idx & 31;
        int s = idx >> 5;
        float inv = powf(10000.0f, -(2.0f * i) / 64.0f);
        float ang = (float)s * inv;
        float c = cosf(ang), sn = sinf(ang);
        const ushort_t* p = cat16r + (size_t)s * 2176 + Q_LORA + KV_LORA;
        ushort_t* q = kpe16 + (size_t)s * D_ROPE;
        float x1 = bf2f(p[i]), x2 = bf2f(p[i + 32]);
        q[i]      = f2bf(x1 * c - x2 * sn);
        q[i + 32] = f2bf(x2 * c + x1 * sn);
    }
}

// ---------------- V transpose: kv16[s][h*256+128+dv] -> v16t[h][dv][s] ----------------
__global__ __launch_bounds__(256) void conv_vT_kernel(
    const ushort_t* __restrict__ kv, ushort_t* __restrict__ v16t)
{
    __shared__ ushort_t tile[32][33];
    const int h = blockIdx.z;
    const int s0 = blockIdx.x * 32, d0 = blockIdx.y * 32;
    const int tr = threadIdx.x >> 5, tc = threadIdx.x & 31;
    #pragma unroll
    for (int i = 0; i < 4; ++i) {
        int r = tr + i * 8;  // s
        tile[r][tc] = kv[(size_t)(s0 + r) * 4096 + h * 256 + D_NOPE + d0 + tc];
    }
    __syncthreads();
    #pragma unroll
    for (int i = 0; i < 4; ++i) {
        int r = tr + i * 8;  // dv
        v16t[(size_t)h * D_V * S_LEN + (size_t)(d0 + r) * S_LEN + s0 + tc] = tile[tc][r];
    }
}

// ---- GEMM body A: 128x128 tile, 2-DEEP counted-vmcnt pipeline, 64 KB LDS.
// For grid-starved GEMMs (~1 block/CU): in-block pipeline is the only overlap. ----
template <typename CT>
__device__ __forceinline__ void gemm_body_128(
    const ushort_t* __restrict__ A, const ushort_t* __restrict__ Bt,
    CT* __restrict__ C, int N, int K, int m0, int n0,
    ushort_t* Al, ushort_t* Bl)  // each 2 bufs * 8192 ushorts = 32 KB
{
    const int tid = threadIdx.x;
    const int lane = tid & 63;
    const int w = tid >> 6;
    const int lm = lane & 15, quad = lane >> 4;
    const int wr = w >> 1, wc = w & 1;

    f32x4 acc[4][4];
    #pragma unroll
    for (int a = 0; a < 4; ++a)
        #pragma unroll
        for (int b = 0; b < 4; ++b) acc[a][b] = (f32x4){0.f, 0.f, 0.f, 0.f};

    const int rrow = tid >> 2;                                // 0..63
    const int rcsw = ((tid & 3) ^ ((tid >> 3) & 3)) * 8;      // swizzled source k-slot
    const int swq  = quad ^ ((lm >> 1) & 3);                  // swizzled read slot

    const int NT = K >> 6;

    auto stage = [&](int buf, int k0) {
        #pragma unroll
        for (int c = 0; c < 2; ++c)
            #pragma unroll
            for (int half = 0; half < 2; ++half) {
                gload_lds16(A + (size_t)(m0 + half * 64 + rrow) * K + k0 + c * 32 + rcsw,
                            Al + buf * 8192 + c * 4096 + half * 2048 + tid * 8);
                gload_lds16(Bt + (size_t)(n0 + half * 64 + rrow) * K + k0 + c * 32 + rcsw,
                            Bl + buf * 8192 + c * 4096 + half * 2048 + tid * 8);
            }
    };

    stage(0, 0);       // 8 loads/wave
    stage(1, 64);      // +8 (NT >= 8 for all our shapes)

    int cur = 0;
    for (int t = 0; t < NT; ++t) {
        if (t + 1 < NT) asm volatile("s_waitcnt vmcnt(8)" ::: "memory");
        else            asm volatile("s_waitcnt vmcnt(0)" ::: "memory");
        __builtin_amdgcn_s_barrier();
        __builtin_amdgcn_sched_barrier(0);

        const ushort_t* Ab = Al + cur * 8192;
        const ushort_t* Bb = Bl + cur * 8192;
        #pragma unroll
        for (int c = 0; c < 2; ++c) {
            short8 af[4], bf[4];
            #pragma unroll
            for (int t2 = 0; t2 < 4; ++t2)
                af[t2] = *(const short8*)(Ab + c * 4096 + (wr * 64 + t2 * 16 + lm) * 32 + swq * 8);
            #pragma unroll
            for (int t2 = 0; t2 < 4; ++t2)
                bf[t2] = *(const short8*)(Bb + c * 4096 + (wc * 64 + t2 * 16 + lm) * 32 + swq * 8);
            #pragma unroll
            for (int mt = 0; mt < 4; ++mt)
                #pragma unroll
                for (int nt = 0; nt < 4; ++nt)
                    acc[mt][nt] = __builtin_amdgcn_mfma_f32_16x16x32_bf16(
                        af[mt], bf[nt], acc[mt][nt], 0, 0, 0);
        }

        __builtin_amdgcn_s_barrier();       // all waves done reading buf cur
        __builtin_amdgcn_sched_barrier(0);
        if (t + 2 < NT) stage(cur, (t + 2) << 6);   // overwrite released buffer
        cur ^= 1;
    }

    #pragma unroll
    for (int mt = 0; mt < 4; ++mt)
        #pragma unroll
        for (int nt = 0; nt < 4; ++nt)
            #pragma unroll
            for (int r = 0; r < 4; ++r) {
                int row = m0 + wr * 64 + mt * 16 + quad * 4 + r;
                int col = n0 + wc * 64 + nt * 16 + lm;
                storeC(&C[(size_t)row * N + col], acc[mt][nt][r]);
            }
}

// ---- GEMM body B: 128x128 tile, SINGLE-buffer 32 KB LDS, plain 2-barrier.
// For occupancy-rich grids (GEMM4, 896 blocks): 32 KB -> 4-5 blocks/CU and
// cross-block overlap (m114 mechanism) masks the drain better than an
// in-block pipeline at 2 blocks/CU. ----
template <typename CT>
__device__ __forceinline__ void gemm_body_128_sb(
    const ushort_t* __restrict__ A, const ushort_t* __restrict__ Bt,
    CT* __restrict__ C, int N, int K, int m0, int n0,
    ushort_t* Al, ushort_t* Bl)  // each 8192 ushorts = 16 KB
{
    const int tid = threadIdx.x;
    const int lane = tid & 63;
    const int w = tid >> 6;
    const int lm = lane & 15, quad = lane >> 4;
    const int wr = w >> 1, wc = w & 1;

    f32x4 acc[4][4];
    #pragma unroll
    for (int a = 0; a < 4; ++a)
        #pragma unroll
        for (int b = 0; b < 4; ++b) acc[a][b] = (f32x4){0.f, 0.f, 0.f, 0.f};

    const int rrow = tid >> 2;
    const int rcsw = ((tid & 3) ^ ((tid >> 3) & 3)) * 8;
    const int swq  = quad ^ ((lm >> 1) & 3);

    for (int k0 = 0; k0 < K; k0 += 64) {
        __syncthreads();
        #pragma unroll
        for (int c = 0; c < 2; ++c)
            #pragma unroll
            for (int half = 0; half < 2; ++half) {
                gload_lds16(A + (size_t)(m0 + half * 64 + rrow) * K + k0 + c * 32 + rcsw,
                            Al + c * 4096 + half * 2048 + tid * 8);
                gload_lds16(Bt + (size_t)(n0 + half * 64 + rrow) * K + k0 + c * 32 + rcsw,
                            Bl + c * 4096 + half * 2048 + tid * 8);
            }
        __syncthreads();

        #pragma unroll
        for (int c = 0; c < 2; ++c) {
            short8 af[4], bf[4];
            #pragma unroll
            for (int t2 = 0; t2 < 4; ++t2)
                af[t2] = *(const short8*)(Al + c * 4096 + (wr * 64 + t2 * 16 + lm) * 32 + swq * 8);
            #pragma unroll
            for (int t2 = 0; t2 < 4; ++t2)
                bf[t2] = *(const short8*)(Bl + c * 4096 + (wc * 64 + t2 * 16 + lm) * 32 + swq * 8);
            #pragma unroll
            for (int mt = 0; mt < 4; ++mt)
                #pragma unroll
                for (int nt = 0; nt < 4; ++nt)
                    acc[mt][nt] = __builtin_amdgcn_mfma_f32_16x16x32_bf16(
                        af[mt], bf[nt], acc[mt][nt], 0, 0, 0);
        }
    }

    #pragma unroll
    for (int mt = 0; mt < 4; ++mt)
        #pragma unroll
        for (int nt = 0; nt < 4; ++nt)
            #pragma unroll
            for (int r = 0; r < 4; ++r) {
                int row = m0 + wr * 64 + mt * 16 + quad * 4 + r;
                int col = n0 + wc * 64 + nt * 16 + lm;
                storeC(&C[(size_t)row * N + col], acc[mt][nt][r]);
            }
}

template <typename CT>
__global__ __launch_bounds__(256) void mfma_gemm_bt(
    const ushort_t* __restrict__ A, const ushort_t* __restrict__ Bt,
    CT* __restrict__ C, int N, int K)
{
    __shared__ ushort_t Al[2 * 8192];
    __shared__ ushort_t Bl[2 * 8192];
    gemm_body_128<CT>(A, Bt, C, N, K, blockIdx.y * 128, blockIdx.x * 128, Al, Bl);
}

__global__ __launch_bounds__(256) void mfma_gemm_dual(
    const ushort_t* __restrict__ A1, const ushort_t* __restrict__ Bt1,
    ushort_t* __restrict__ C1, int N1, int K1, int nb1,
    const ushort_t* __restrict__ A2, const ushort_t* __restrict__ Bt2,
    ushort_t* __restrict__ C2, int N2, int K2)
{
    __shared__ ushort_t Al[8192];
    __shared__ ushort_t Bl[8192];
    int g = blockIdx.x;
    if (g < nb1) {
        int nbx = N1 / 128;
        gemm_body_128_sb<ushort_t>(A1, Bt1, C1, N1, K1, (g / nbx) * 128, (g % nbx) * 128, Al, Bl);
    } else {
        g -= nb1;
        int nbx = N2 / 128;
        gemm_body_128_sb<ushort_t>(A2, Bt2, C2, N2, K2, (g / nbx) * 128, (g % nbx) * 128, Al, Bl);
    }
}

// online-softmax update for one 16x64 score tile in C layout (DPP); P -> ps[16][72].
// MASKED=false for interior tiles (k0+63 <= qw): no causal cndmask needed.
// T13 defer-rescale (THR=8): when no row max grew by >8, keep old m and skip
// the O-rescale entirely (alpha == 1 exactly).
template <bool MASKED>
__device__ __forceinline__ void softmax_step_t(
    f32x4 s[4], int k0, int qw, int lm, int quad,
    float m_[4], float l_[4], f32x4 O[8], ushort_t* ps)
{
    const float scale = 0.07216878364870322f;  // 192^-0.5
    float a[4][4];
    float pmax[4];
    float worst = -1e30f;
    #pragma unroll
    for (int r = 0; r < 4; ++r) {
        int qrow = qw + quad * 4 + r;
        #pragma unroll
        for (int st = 0; st < 4; ++st) {
            float v = s[st][r] * scale;
            if (MASKED) v = (k0 + st * 16 + lm <= qrow) ? v : -1e30f;
            a[r][st] = v;
        }
        pmax[r] = dpp_max16(fmaxf(fmaxf(a[r][0], a[r][1]), fmaxf(a[r][2], a[r][3])));
        worst = fmaxf(worst, pmax[r] - m_[r]);
    }
    if (__all(worst <= 8.0f)) {
        // deferred: keep m_, alpha == 1, no O-rescale
        #pragma unroll
        for (int r = 0; r < 4; ++r) {
            float p[4];
            #pragma unroll
            for (int st = 0; st < 4; ++st) p[st] = __expf(a[r][st] - m_[r]);
            l_[r] += dpp_sum16((p[0] + p[1]) + (p[2] + p[3]));
            #pragma unroll
            for (int st = 0; st < 4; ++st)
                ps[(quad * 4 + r) * 72 + st * 16 + lm] = f2bf(p[st]);
        }
    } else {
        #pragma unroll
        for (int r = 0; r < 4; ++r) {
            float mn = fmaxf(m_[r], pmax[r]);
            float p[4];
            #pragma unroll
            for (int st = 0; st < 4; ++st) p[st] = __expf(a[r][st] - mn);
            float alpha = __expf(m_[r] - mn);
            float psum = dpp_sum16((p[0] + p[1]) + (p[2] + p[3]));
            l_[r] = l_[r] * alpha + psum;
            m_[r] = mn;
            #pragma unroll
            for (int c = 0; c < 8; ++c) O[c][r] *= alpha;
            #pragma unroll
            for (int st = 0; st < 4; ++st)
                ps[(quad * 4 + r) * 72 + st * 16 + lm] = f2bf(p[st]);
        }
    }
}

// ---- MFMA flash attention: QBLK=64 / 4 waves / KVBLK=64, split-staging
// counted-vmcnt pipeline (round-5, validated 92->80 µs), plus:
//  * BALANCED PAIRED GRID: flattened 512-block grid; dispatch order o pairs
//    (o, o+256) onto the same CU slot; q-tile map ty = oy<16 ? oy : 47-oy
//    makes every pair sum to exactly 33 tiles (was 48 worst-case).
//  * mask-free softmax for interior tiles, T13 defer-rescale (THR=8). ----
__global__ __launch_bounds__(256) void mla_attn_kernel(
    const ushort_t* __restrict__ qb, const ushort_t* __restrict__ kvb,
    const ushort_t* __restrict__ kpe, const ushort_t* __restrict__ v16t,
    ushort_t* __restrict__ aout16)
{
    __shared__ ushort_t Kn[2 * 4 * 64 * 32];   // 32 KB (2 bufs)
    __shared__ ushort_t Kr[2 * 2 * 64 * 32];   // 16 KB (2 bufs)
    __shared__ ushort_t Vt[2 * 128 * 32];      // 16 KB (single buf)
    __shared__ ushort_t Ps[4][16 * 72];        //  9 KB

    const int o = blockIdx.x;
    const int h = o & 15;
    const int oy = o >> 4;                       // dispatch-order tile slot 0..31
    const int ty = (oy < 16) ? oy : 47 - oy;     // balanced pairing: ty + ty' = 31
    const int q0 = 64 * (31 - ty);               // heavy-first within first round
    const int w = threadIdx.x >> 6;              // 0..3
    const int lane = threadIdx.x & 63;
    const int lm = lane & 15, quad = lane >> 4;
    const int qw = q0 + 16 * w;
    ushort_t* myPs = Ps[w];

    const int skey = lane >> 2;                               // 0..15
    const int ssw  = ((lane & 3) ^ ((lane >> 3) & 3)) * 8;    // swizzled source slot
    const int swq  = quad ^ ((lm >> 1) & 3);                  // swizzled read slot

    // Q fragments (un-roped source) + fused RoPE on chunks 4/5
    short8 qf[6];
    #pragma unroll
    for (int f = 0; f < 6; ++f)
        qf[f] = *(const short8*)(qb + (size_t)(qw + lm) * 3072 + h * 192 + f * 32 + quad * 8);
    {
        float srow = (float)(qw + lm);
        #pragma unroll
        for (int j = 0; j < 8; ++j) {
            int i = quad * 8 + j;
            float inv = powf(10000.0f, -(2.0f * i) / 64.0f);
            float ang = srow * inv;
            float c = cosf(ang), sn = sinf(ang);
            float x1 = bf2f((ushort_t)qf[4][j]);
            float x2 = bf2f((ushort_t)qf[5][j]);
            qf[4][j] = (short)f2bf(x1 * c - x2 * sn);
            qf[5][j] = (short)f2bf(x2 * c + x1 * sn);
        }
    }
    // drain Q loads so vmcnt bookkeeping below is exact
    asm volatile("s_waitcnt vmcnt(0)" ::: "memory");

    f32x4 O[8];
    #pragma unroll
    for (int c = 0; c < 8; ++c) O[c] = (f32x4){0.f, 0.f, 0.f, 0.f};
    float m_[4] = {-1e30f, -1e30f, -1e30f, -1e30f};
    float l_[4] = {0.f, 0.f, 0.f, 0.f};

    // per-wave staging: Kn 4 loads, Kr 2 loads, V 4 loads
    auto stageK = [&](int buf, int k0s) {
        #pragma unroll
        for (int i = 0; i < 4; ++i)
            gload_lds16(kvb + (size_t)(k0s + i * 16 + skey) * 4096 + h * 256 + w * 32 + ssw,
                        Kn + buf * 8192 + w * 2048 + i * 512 + lane * 8);
        #pragma unroll
        for (int ii = 0; ii < 2; ++ii) {
            int i = 2 * (w & 1) + ii;
            gload_lds16(kpe + (size_t)(k0s + i * 16 + skey) * 64 + (w >> 1) * 32 + ssw,
                        Kr + buf * 4096 + (w >> 1) * 2048 + i * 512 + lane * 8);
        }
    };
    auto stageV = [&](int k0s) {
        #pragma unroll
        for (int jj = 0; jj < 4; ++jj) {
            int j = 4 * (w >> 1) + jj;
            gload_lds16(v16t + ((size_t)h * 128 + j * 16 + skey) * S_LEN + k0s + (w & 1) * 32 + ssw,
                        Vt + (w & 1) * 4096 + j * 512 + lane * 8);
        }
    };

    const int nt = q0 / 64 + 1;
    stageK(0, 0);   // 6 outstanding/wave

    for (int t = 0; t < nt; ++t) {
        const int k0 = t * 64;
        const bool hasNext = (t + 1 < nt);
        const int kb = t & 1;

        stageV(k0);                                // +4
        if (hasNext) stageK(kb ^ 1, k0 + 64);      // +6

        if (hasNext) asm volatile("s_waitcnt vmcnt(10)" ::: "memory");  // K(t) landed
        else         asm volatile("s_waitcnt vmcnt(4)"  ::: "memory");
        __builtin_amdgcn_s_barrier();
        __builtin_amdgcn_sched_barrier(0);

        // ---- QK^T from Kn/Kr buf kb ----
        f32x4 s[4];
        #pragma unroll
        for (int st = 0; st < 4; ++st) s[st] = (f32x4){0.f, 0.f, 0.f, 0.f};
        #pragma unroll
        for (int f = 0; f < 4; ++f)
            #pragma unroll
            for (int st = 0; st < 4; ++st) {
                short8 kf = *(const short8*)(Kn + kb * 8192 + f * 2048 + (st * 16 + lm) * 32 + swq * 8);
                s[st] = __builtin_amdgcn_mfma_f32_16x16x32_bf16(qf[f], kf, s[st], 0, 0, 0);
            }
        #pragma unroll
        for (int f2 = 0; f2 < 2; ++f2)
            #pragma unroll
            for (int st = 0; st < 4; ++st) {
                short8 kf = *(const short8*)(Kr + kb * 4096 + f2 * 2048 + (st * 16 + lm) * 32 + swq * 8);
                s[st] = __builtin_amdgcn_mfma_f32_16x16x32_bf16(qf[4 + f2], kf, s[st], 0, 0, 0);
            }

        if (k0 + 63 <= qw) softmax_step_t<false>(s, k0, qw, lm, quad, m_, l_, O, myPs);
        else               softmax_step_t<true >(s, k0, qw, lm, quad, m_, l_, O, myPs);

        // V(t) landed (K(t+1) still in flight) + own Ps writes visible
        if (hasNext) asm volatile("s_waitcnt vmcnt(6) lgkmcnt(0)" ::: "memory");
        else         asm volatile("s_waitcnt vmcnt(0) lgkmcnt(0)" ::: "memory");
        __builtin_amdgcn_s_barrier();
        __builtin_amdgcn_sched_barrier(0);

        short8 pf0 = *(const short8*)(myPs + lm * 72 + quad * 8);
        short8 pf1 = *(const short8*)(myPs + lm * 72 + 32 + quad * 8);
        #pragma unroll
        for (int c = 0; c < 8; ++c) {
            short8 vf0 = *(const short8*)(Vt + (c * 16 + lm) * 32 + swq * 8);
            short8 vf1 = *(const short8*)(Vt + 4096 + (c * 16 + lm) * 32 + swq * 8);
            O[c] = __builtin_amdgcn_mfma_f32_16x16x32_bf16(pf0, vf0, O[c], 0, 0, 0);
            O[c] = __builtin_amdgcn_mfma_f32_16x16x32_bf16(pf1, vf1, O[c], 0, 0, 0);
        }

        __builtin_amdgcn_s_barrier();   // release Vt and Kn/Kr[kb] for next iter's staging
        __builtin_amdgcn_sched_barrier(0);
    }

    // epilogue
    #pragma unroll
    for (int c = 0; c < 8; ++c)
        #pragma unroll
        for (int r = 0; r < 4; ++r) {
            int qrow = qw + quad * 4 + r;
            aout16[(size_t)qrow * 2048 + h * D_V + c * 16 + lm] = f2bf(O[c][r] / l_[r]);
        }
}

extern "C" void kernel_launch(void* const* d_in, const int* in_sizes, int n_in,
                              void* d_out, int out_size, void* d_ws, size_t ws_size,
                              hipStream_t stream)
{
    (void)in_sizes; (void)n_in; (void)out_size; (void)ws_size;
    const float* hs   = (const float*)d_in[0];
    const float* Wqa  = (const float*)d_in[1];
    const float* qlnw = (const float*)d_in[2];
    const float* Wqb  = (const float*)d_in[3];
    const float* Wkva = (const float*)d_in[4];
    const float* klnw = (const float*)d_in[5];
    const float* Wkvb = (const float*)d_in[6];
    const float* Wo   = (const float*)d_in[7];
    float* out = (float*)d_out;

    ushort_t* p = (ushort_t*)d_ws;
    ushort_t* hs16   = p; p += (size_t)S_LEN * H_DIM;
    ushort_t* WcatT  = p; p += (size_t)2176 * H_DIM;     // [Wqa^T 1536 ; Wkva^T 640] x 2048
    ushort_t* WqbT   = p; p += (size_t)3072 * Q_LORA;
    ushort_t* WkvbT  = p; p += (size_t)4096 * KV_LORA;
    ushort_t* WoT    = p; p += (size_t)H_DIM * H_DIM;
    ushort_t* cat16r = p; p += (size_t)S_LEN * 2176;     // [qa_raw | ckv_raw | kpe_raw | pad]
    ushort_t* qa16   = p; p += (size_t)S_LEN * Q_LORA;
    ushort_t* qbuf16 = p; p += (size_t)S_LEN * 3072;
    ushort_t* ckv16n = p; p += (size_t)S_LEN * KV_LORA;
    ushort_t* kpe16  = p; p += (size_t)S_LEN * D_ROPE;
    ushort_t* kv16   = p; p += (size_t)S_LEN * 4096;
    ushort_t* v16t   = p; p += (size_t)NH * D_V * S_LEN;
    ushort_t* aout16 = p; p += (size_t)S_LEN * 2048;

    // 1. all conversions in one launch (hs + 5 weight transposes)
    unified_conv<<<19200, 256, 0, stream>>>(
        hs, hs16, Wqa, Wkva, Wqb, Wkvb, Wo, WcatT, WqbT, WkvbT, WoT);
    // 2. cat16r = hs16 @ WcatT^T  [2048 x 2176, K=2048]  (fused Wqa + Wkva)
    mfma_gemm_bt<ushort_t><<<dim3(2176 / 128, S_LEN / 128), 256, 0, stream>>>(
        hs16, WcatT, cat16r, 2176, H_DIM);
    // 3. fused rmsnorm-q / rmsnorm-kv / rope-k
    fused_norm_ropek<<<4096 + 256, 256, 0, stream>>>(cat16r, qa16, ckv16n, kpe16, qlnw, klnw);
    // 4. grouped GEMM (single-buffer 32 KB body, 4+ blocks/CU): qbuf16 + kv16
    mfma_gemm_dual<<<384 + 512, 256, 0, stream>>>(
        qa16, WqbT, qbuf16, 3072, Q_LORA, 384,
        ckv16n, WkvbT, kv16, 4096, KV_LORA);
    // 5. V transpose
    conv_vT_kernel<<<dim3(S_LEN / 32, D_V / 32, NH), 256, 0, stream>>>(kv16, v16t);
    // 6. attention (balanced paired grid, split-staging pipeline, trimmed softmax)
    mla_attn_kernel<<<512, 256, 0, stream>>>(qbuf16, kv16, kpe16, v16t, aout16);
    // 7. out = aout16 @ WoT^T [2048 x 2048, K=2048], fp32 store
    mfma_gemm_bt<float><<<dim3(H_DIM / 128, S_LEN / 128), 256, 0, stream>>>(
        aout16, WoT, out, H_DIM, H_DIM);
}